// Round 3
// baseline (1857.102 us; speedup 1.0000x reference)
//
#include <hip/hip_runtime.h>
#include <hip/hip_bf16.h>
#include <math.h>

typedef __attribute__((ext_vector_type(8))) short short8;
typedef __attribute__((ext_vector_type(4))) float f32x4;
typedef unsigned short ushortT;

// ---------- helpers ----------
__device__ __forceinline__ unsigned short f2b(float f) {
  union { float f; unsigned u; } v; v.f = f;
  return (unsigned short)((v.u + 0x7FFFu + ((v.u >> 16) & 1u)) >> 16);
}
__device__ __forceinline__ float b2f(unsigned short h) {
  union { unsigned u; float f; } v; v.u = ((unsigned)h) << 16;
  return v.f;
}
__device__ __forceinline__ float gelu_f(float x) {
  return 0.5f * x * (1.0f + tanhf(0.7978845608028654f * (x + 0.044715f * x * x * x)));
}
__device__ __forceinline__ float cvt_in(float x) { return x; }
__device__ __forceinline__ float cvt_in(unsigned short x) { return b2f(x); }

// ---------- GEMM: C(M,N) = A(M,K) @ Bt(N,K)^T, bf16 in/out, f32 acc ----------
// 128x128 tile, BK=32, 4 waves of 64x64, mfma_f32_16x16x32_bf16
// bmode: 0=no bias, 1=bias[col] (f32), 2=bias[row] (f32)
template<bool GELU>
__global__ __launch_bounds__(256)
void gemm_bt(const ushortT* __restrict__ A, const ushortT* __restrict__ Bt,
             ushortT* __restrict__ C, const float* __restrict__ bias, int bmode,
             int M, int N, int K, long sA, long sB, long sC)
{
  __shared__ ushortT lA[128 * 40];   // 32+8 pad -> 16B-aligned conflict-free b128
  __shared__ ushortT lB[128 * 40];
  const int z = blockIdx.z;
  A += (long)z * sA;
  Bt += (long)z * sB;
  const long coff = (long)z * sC;
  const int bm = blockIdx.y * 128, bn = blockIdx.x * 128;
  const int tid = threadIdx.x;
  const int wave = tid >> 6, lane = tid & 63;
  const int wm = (wave >> 1) << 6, wn = (wave & 1) << 6;
  const int l15 = lane & 15, quad = lane >> 4;
  const int tr = tid >> 1, th = (tid & 1) << 4;

  f32x4 acc[4][4];
#pragma unroll
  for (int i = 0; i < 4; ++i)
#pragma unroll
    for (int j = 0; j < 4; ++j) acc[i][j] = (f32x4){0.f, 0.f, 0.f, 0.f};

  const int ra = bm + tr;
  const int rb = bn + tr;
  const bool va = (ra < M), vb = (rb < N);
  const ushortT* pa = A + (long)ra * K + th;
  const ushortT* pb = Bt + (long)rb * K + th;
  const uint4 zero4 = {0u, 0u, 0u, 0u};

  for (int k0 = 0; k0 < K; k0 += 32) {
    uint4 ua0 = va ? *(const uint4*)(pa + k0) : zero4;
    uint4 ua1 = va ? *(const uint4*)(pa + k0 + 8) : zero4;
    uint4 ub0 = vb ? *(const uint4*)(pb + k0) : zero4;
    uint4 ub1 = vb ? *(const uint4*)(pb + k0 + 8) : zero4;
    *(uint4*)&lA[tr * 40 + th] = ua0;
    *(uint4*)&lA[tr * 40 + th + 8] = ua1;
    *(uint4*)&lB[tr * 40 + th] = ub0;
    *(uint4*)&lB[tr * 40 + th + 8] = ub1;
    __syncthreads();
    short8 aF[4], bF[4];
#pragma unroll
    for (int t = 0; t < 4; ++t)
      aF[t] = *(const short8*)&lA[(wm + t * 16 + l15) * 40 + (quad << 3)];
#pragma unroll
    for (int t = 0; t < 4; ++t)
      bF[t] = *(const short8*)&lB[(wn + t * 16 + l15) * 40 + (quad << 3)];
#pragma unroll
    for (int i = 0; i < 4; ++i)
#pragma unroll
      for (int j = 0; j < 4; ++j)
        acc[i][j] = __builtin_amdgcn_mfma_f32_16x16x32_bf16(aF[i], bF[j], acc[i][j], 0, 0, 0);
    __syncthreads();
  }

#pragma unroll
  for (int j = 0; j < 4; ++j) {
    int col = bn + wn + j * 16 + l15;
    if (col >= N) continue;
    float cbv = (bmode == 1) ? bias[col] : 0.0f;
#pragma unroll
    for (int i = 0; i < 4; ++i) {
      int row0 = bm + wm + i * 16 + (quad << 2);
#pragma unroll
      for (int r = 0; r < 4; ++r) {
        int row = row0 + r;
        if (row >= M) continue;
        float bv = (bmode == 2) ? bias[row] : cbv;
        float v = acc[i][j][r] + bv;
        if (GELU) v = gelu_f(v);
        C[coff + (long)row * N + col] = f2b(v);
      }
    }
  }
}

// ---------- batched tiled transpose (z,R,C) -> (z,C,R) bf16 out, optional gather ----------
template<typename TIn>
__global__ void btrans(const TIn* __restrict__ in, ushortT* __restrict__ out,
                       int R, int C, const int* __restrict__ gather) {
  __shared__ float tile[32][33];
  int z = blockIdx.z;
  long ib = (long)(gather ? gather[z] : z) * (long)R * C;
  long ob = (long)z * (long)R * C;
  int c0 = blockIdx.x << 5, r0 = blockIdx.y << 5;
  int tx = threadIdx.x, ty = threadIdx.y;
#pragma unroll
  for (int dy = 0; dy < 32; dy += 8)
    tile[ty + dy][tx] = cvt_in(in[ib + (long)(r0 + ty + dy) * C + c0 + tx]);
  __syncthreads();
#pragma unroll
  for (int dy = 0; dy < 32; dy += 8)
    out[ob + (long)(c0 + ty + dy) * R + r0 + tx] = f2b(tile[tx][ty + dy]);
}

// ---------- f32 -> bf16 convert ----------
__global__ void conv_f2b(const float4* __restrict__ in, uint2* __restrict__ out, long n4) {
  long i = (long)blockIdx.x * 256 + threadIdx.x;
  if (i >= n4) return;
  float4 v = in[i];
  uint2 r;
  r.x = (unsigned)f2b(v.x) | ((unsigned)f2b(v.y) << 16);
  r.y = (unsigned)f2b(v.z) | ((unsigned)f2b(v.w) << 16);
  out[i] = r;
}

// ---------- RoPE: bf16 (rows,512) -> bf16, pos = row % 1024 ----------
__global__ __launch_bounds__(256)
void rope_k(const unsigned* __restrict__ in, unsigned* __restrict__ out) {
  int row = blockIdx.x;
  int i = threadIdx.x;                 // pair index 0..255
  int pos = row & 1023;
  float inv = __expf(-(float)i * 0.035977892078032f); // 10000^(-2i/512)
  float sn, cs;
  sincosf((float)pos * inv, &sn, &cs);
  unsigned u = in[(long)row * 256 + i];
  float x1 = b2f((unsigned short)(u & 0xFFFFu));
  float x2 = b2f((unsigned short)(u >> 16));
  float o1 = x1 * cs - x2 * sn;
  float o2 = x1 * sn + x2 * cs;
  out[(long)row * 256 + i] = (unsigned)f2b(o1) | ((unsigned)f2b(o2) << 16);
}

// ---------- in-place softmax rows: x = softmax(x*scale + bias), bias 0/log/logit (f32) ----------
__global__ __launch_bounds__(256)
void softmax_k(ushortT* __restrict__ x, const float* __restrict__ pbias,
               int bias_mode, int L, int rows_per_batch, float scale)
{
  __shared__ float v[1024];
  __shared__ float red[256];
  int row = blockIdx.x, tid = threadIdx.x;
  ushortT* xr = x + (long)row * L;
  const float* bb = pbias ? pbias + (long)(row / rows_per_batch) * L : nullptr;
  float lmax = -3.0e38f;
  for (int j = tid; j < L; j += 256) {
    float b = 0.f;
    if (bias_mode == 1) b = __logf(bb[j]);
    else if (bias_mode == 2) { float p = bb[j]; b = __logf(p) - log1pf(-p); }
    float t = b2f(xr[j]) * scale + b;
    v[j] = t;
    lmax = fmaxf(lmax, t);
  }
  red[tid] = lmax; __syncthreads();
  for (int s = 128; s > 0; s >>= 1) { if (tid < s) red[tid] = fmaxf(red[tid], red[tid + s]); __syncthreads(); }
  float m = red[0];
  __syncthreads();
  float lsum = 0.f;
  for (int j = tid; j < L; j += 256) { float e = __expf(v[j] - m); v[j] = e; lsum += e; }
  red[tid] = lsum; __syncthreads();
  for (int s = 128; s > 0; s >>= 1) { if (tid < s) red[tid] += red[tid + s]; __syncthreads(); }
  float inv = 1.0f / red[0];
  for (int j = tid; j < L; j += 256) xr[j] = f2b(v[j] * inv);
}

// ---------- fused residual + LayerNorm on bf16 state (D=512), f32 gamma/beta ----------
__global__ __launch_bounds__(256)
void ln_k(ushortT* __restrict__ xb, const ushortT* __restrict__ res,
          const float* __restrict__ gamma, const float* __restrict__ beta)
{
  __shared__ float red[256];
  int row = blockIdx.x, tid = threadIdx.x;
  long off = (long)row * 512;
  float a = b2f(xb[off + tid]) + b2f(res[off + tid]);
  float b = b2f(xb[off + tid + 256]) + b2f(res[off + tid + 256]);
  red[tid] = a + b; __syncthreads();
  for (int s = 128; s > 0; s >>= 1) { if (tid < s) red[tid] += red[tid + s]; __syncthreads(); }
  float mean = red[0] * (1.0f / 512.0f);
  __syncthreads();
  float da = a - mean, db = b - mean;
  red[tid] = da * da + db * db; __syncthreads();
  for (int s = 128; s > 0; s >>= 1) { if (tid < s) red[tid] += red[tid + s]; __syncthreads(); }
  float rstd = rsqrtf(red[0] * (1.0f / 512.0f) + 1e-5f);
  xb[off + tid]       = f2b(da * rstd * gamma[tid]       + beta[tid]);
  xb[off + tid + 256] = f2b(db * rstd * gamma[tid + 256] + beta[tid + 256]);
}

// ---------- v = raw * sigmoid(for_ignore @ W_ig + b_ig), bf16 out ----------
__global__ __launch_bounds__(256)
void gatev_k(const ushortT* __restrict__ fi, const float* __restrict__ raw,
             const float* __restrict__ wig, const float* __restrict__ big,
             ushortT* __restrict__ vout)
{
  __shared__ float red[256];
  int row = blockIdx.x, tid = threadIdx.x;
  long off = (long)row * 512;
  red[tid] = b2f(fi[off + tid]) * wig[tid] + b2f(fi[off + tid + 256]) * wig[tid + 256];
  __syncthreads();
  for (int s = 128; s > 0; s >>= 1) { if (tid < s) red[tid] += red[tid + s]; __syncthreads(); }
  float g = 1.0f / (1.0f + __expf(-(red[0] + big[0])));
  vout[off + tid]       = f2b(raw[off + tid] * g);
  vout[off + tid + 256] = f2b(raw[off + tid + 256] * g);
}

// ---------- final gating + output write (f32 out) ----------
__global__ __launch_bounds__(256)
void final_k(const ushortT* __restrict__ fu, const ushortT* __restrict__ A2,
             const float* __restrict__ pd, const float* __restrict__ wu1,
             const float* __restrict__ wu2, const float* __restrict__ bu1,
             const float* __restrict__ bu2, const float* __restrict__ b1p,
             float* __restrict__ outx, float* __restrict__ outg)
{
  __shared__ float r1[256], r2[256];
  int row = blockIdx.x, tid = threadIdx.x;
  long off = (long)row * 512;
  float a2a = b2f(A2[off + tid]), a2b = b2f(A2[off + tid + 256]);
  r1[tid] = b2f(fu[off + tid]) * wu1[tid] + b2f(fu[off + tid + 256]) * wu1[tid + 256];
  r2[tid] = a2a * wu2[tid] + a2b * wu2[tid + 256];
  __syncthreads();
  for (int s = 128; s > 0; s >>= 1) {
    if (tid < s) { r1[tid] += r1[tid + s]; r2[tid] += r2[tid + s]; }
    __syncthreads();
  }
  float g = 1.0f / (1.0f + __expf(-(r1[0] + r2[0] + bu1[0] + bu2[0] + b1p[0] - 4.0f)));
  outx[off + tid]       = pd[off + tid] * (1.0f - g) + a2a * g;
  outx[off + tid + 256] = pd[off + tid + 256] * (1.0f - g) + a2b * g;
  if (tid == 0) outg[row] = g;
}

// ================= host orchestration =================
extern "C" void kernel_launch(void* const* d_in, const int* in_sizes, int n_in,
                              void* d_out, int out_size, void* d_ws, size_t ws_size,
                              hipStream_t stream)
{
  const float* raw_emb = (const float*)d_in[0];
  const float* rpw     = (const float*)d_in[1];
  const float* post_dec= (const float*)d_in[2];
  const float* rpr     = (const float*)d_in[3];
  const float* questions=(const float*)d_in[4];
  const float* W_k  = (const float*)d_in[5];
  const float* W_ig = (const float*)d_in[6];
  const float* b_ig = (const float*)d_in[7];
  const float* W_u1 = (const float*)d_in[8];
  const float* b_u1 = (const float*)d_in[9];
  const float* W_u2 = (const float*)d_in[10];
  const float* b_u2 = (const float*)d_in[11];
  const float* b1   = (const float*)d_in[12];
  const float* W_ok = (const float*)d_in[13];
  const float* b_ok = (const float*)d_in[14];
  const float* ew_qkv = (const float*)d_in[15];
  const float* ew_bqkv= (const float*)d_in[16];
  const float* ew_wo  = (const float*)d_in[17];
  const float* ew_bo  = (const float*)d_in[18];
  const float* ew_ln  = (const float*)d_in[19];
  const float* ew_wff = (const float*)d_in[20];
  const float* ew_bff = (const float*)d_in[21];
  const float* er_qkv = (const float*)d_in[22];
  const float* er_bqkv= (const float*)d_in[23];
  const float* er_wo  = (const float*)d_in[24];
  const float* er_bo  = (const float*)d_in[25];
  const float* er_ln  = (const float*)d_in[26];
  const float* er_wff = (const float*)d_in[27];
  const float* er_bff = (const float*)d_in[28];
  const int* lookup   = (const int*)d_in[29];

  const size_t MAT = 512ull * 512ull;     // elements per 512x512 matrix
  const long SD = 1024 * 512;             // one batch of (1024,512)
  char* wsb = (char*)d_ws;
  size_t off = 0;
  auto alloc = [&](size_t b) { char* p = wsb + off; off = (off + b + 255) & ~(size_t)255; return p; };

  ushortT* WT  = (ushortT*)alloc(26 * MAT * 2);            // transposed bf16 weights
  ushortT* XB  = (ushortT*)alloc(16384ull * 512 * 2);      // encoder state bf16
  ushortT* B1  = (ushortT*)alloc(16384ull * 512 * 2);      // pre-rope q/k, o2, f2, vg
  ushortT* SC  = (ushortT*)alloc(8ull * 1024 * 1024 * 2);  // scores/probs (8-batch chunk)
  ushortT* QB  = (ushortT*)alloc(16384ull * 512 * 2);      // q / o / A2
  ushortT* KB  = (ushortT*)alloc(16384ull * 512 * 2);      // k / f1
  ushortT* VT  = (ushortT*)alloc(16384ull * 512 * 2);      // V^T / vg^T
  ushortT* K2  = (ushortT*)alloc(16384ull * 512 * 2);      // k2 = post_dec @ W_ok
  ushortT* KD  = (ushortT*)alloc(8192ull * 512 * 2);       // k_docs
  ushortT* QSB = (ushortT*)alloc(64ull * 512 * 2);         // questions bf16
  ushortT* SC2 = (ushortT*)alloc(16384ull * 64 * 2);       // A1 scores (8,64,1024) / a2 (16384,64)
  ushortT* A1S = (ushortT*)alloc(8ull * 64 * 512 * 2);     // A1s
  ushortT* SAT = (ushortT*)alloc(16ull * 512 * 64 * 2);    // selA^T

  auto gemm = [&](const ushortT* A, const ushortT* Bt, ushortT* C, const float* bias,
                  int bmode, bool gelu, int M, int N, int K, int Z, long sA, long sB, long sC) {
    dim3 g((N + 127) / 128, (M + 127) / 128, Z);
    if (gelu) gemm_bt<true ><<<g, dim3(256), 0, stream>>>(A, Bt, C, bias, bmode, M, N, K, sA, sB, sC);
    else      gemm_bt<false><<<g, dim3(256), 0, stream>>>(A, Bt, C, bias, bmode, M, N, K, sA, sB, sC);
  };
  auto tw = [&](const float* src, ushortT* dst, int nm) {   // f32 (nm,512,512) -> bf16 W^T
    btrans<float><<<dim3(16, 16, nm), dim3(32, 8), 0, stream>>>(src, dst, 512, 512, nullptr);
  };
  auto conv = [&](const float* src, ushortT* dst, long n) { // n elements, f32 -> bf16
    long n4 = n / 4;
    conv_f2b<<<(unsigned)((n4 + 255) / 256), 256, 0, stream>>>((const float4*)src, (uint2*)dst, n4);
  };

  const float isc512 = 0.044194173824159216f; // 1/sqrt(512)

  // 1. weight transposes
  tw(W_k,    WT + 0 * MAT, 1);
  tw(W_ok,   WT + 1 * MAT, 1);
  tw(ew_qkv, WT + 2 * MAT, 6);
  tw(ew_wo,  WT + 8 * MAT, 2);
  tw(ew_wff, WT + 10 * MAT, 4);
  tw(er_qkv, WT + 14 * MAT, 6);
  tw(er_wo,  WT + 20 * MAT, 2);
  tw(er_wff, WT + 22 * MAT, 4);
  conv(questions, QSB, 64 * 512);

  // encoder driver: XB must hold bf16(x_in) on entry; leaves XB = encoder output
  auto run_enc = [&](int NB, const ushortT* wqkvT, const float* bqkv,
                     const ushortT* woT, const float* bo, const float* lnp,
                     const ushortT* wffT, const float* bff,
                     const float* praw, int bmode) {
    int Mt = NB * 1024;
    for (int l = 0; l < 2; ++l) {
      const ushortT* Wq  = wqkvT + (size_t)(l * 3 + 0) * MAT;
      const ushortT* Wk2 = wqkvT + (size_t)(l * 3 + 1) * MAT;
      const ushortT* Wv  = wqkvT + (size_t)(l * 3 + 2) * MAT;
      gemm(XB, Wq, B1, bqkv + (l * 3 + 0) * 512, 1, false, Mt, 512, 512, 1, 0, 0, 0);
      rope_k<<<Mt, 256, 0, stream>>>((const unsigned*)B1, (unsigned*)QB);
      gemm(XB, Wk2, B1, bqkv + (l * 3 + 1) * 512, 1, false, Mt, 512, 512, 1, 0, 0, 0);
      rope_k<<<Mt, 256, 0, stream>>>((const unsigned*)B1, (unsigned*)KB);
      // V^T directly: C(512,1024) = Wv^T @ X^T per batch, bias per ROW (=output dim)
      gemm(Wv, XB, VT, bqkv + (l * 3 + 2) * 512, 2, false, 512, 1024, 512, NB, 0, SD, SD);
      for (int h = 0; h < NB / 8; ++h) {
        long o5 = (long)h * 8 * SD;
        gemm(QB + o5, KB + o5, SC, nullptr, 0, false, 1024, 1024, 512, 8, SD, SD, 1024 * 1024);
        softmax_k<<<8192, 256, 0, stream>>>(SC, praw + (long)h * 8192, bmode, 1024, 1024, isc512);
        gemm(SC, VT + o5, QB + o5, nullptr, 0, false, 1024, 512, 1024, 8, 1024 * 1024, SD, SD);
      }
      gemm(QB, woT + (size_t)l * MAT, B1, bo + l * 512, 1, false, Mt, 512, 512, 1, 0, 0, 0);
      ln_k<<<Mt, 256, 0, stream>>>(XB, B1, lnp + (l * 4 + 0) * 512, lnp + (l * 4 + 1) * 512);
      gemm(XB, wffT + (size_t)(l * 2 + 0) * MAT, KB, bff + (l * 2 + 0) * 512, 1, true,
           Mt, 512, 512, 1, 0, 0, 0);
      gemm(KB, wffT + (size_t)(l * 2 + 1) * MAT, B1, bff + (l * 2 + 1) * 512, 1, false,
           Mt, 512, 512, 1, 0, 0, 0);
      ln_k<<<Mt, 256, 0, stream>>>(XB, B1, lnp + (l * 4 + 2) * 512, lnp + (l * 4 + 3) * 512);
    }
  };

  // 2. k_docs = raw_emb @ W_k ; encw on raw_emb -> XB = for_ignore
  conv(raw_emb, XB, 8192ull * 512);
  gemm(XB, WT + 0 * MAT, KD, nullptr, 0, false, 8192, 512, 512, 1, 0, 0, 0);
  run_enc(8, WT + 2 * MAT, ew_bqkv, WT + 8 * MAT, ew_bo, ew_ln, WT + 10 * MAT, ew_bff, rpw, 1);

  // 3. v_gate, A1s
  gatev_k<<<8192, 256, 0, stream>>>(XB, raw_emb, W_ig, b_ig, B1);
  btrans<ushortT><<<dim3(16, 32, 8), dim3(32, 8), 0, stream>>>(B1, VT, 1024, 512, nullptr);
  gemm(QSB, KD, SC2, nullptr, 0, false, 64, 1024, 512, 8, 0, SD, 64 * 1024);
  softmax_k<<<512, 256, 0, stream>>>(SC2, rpw, 1, 1024, 64, isc512);
  gemm(SC2, VT, A1S, nullptr, 0, false, 64, 512, 1024, 8, 64 * 1024, SD, 64 * 512);

  // 4. k2 (before encr mutates XB), then encr on post_dec -> XB = for_update
  conv(post_dec, XB, 16384ull * 512);
  gemm(XB, WT + 1 * MAT, K2, b_ok, 1, false, 16384, 512, 512, 1, 0, 0, 0);
  run_enc(16, WT + 14 * MAT, er_bqkv, WT + 20 * MAT, er_bo, er_ln, WT + 22 * MAT, er_bff, rpr, 2);

  // 5. a2, A2
  gemm(K2, QSB, SC2, nullptr, 0, false, 16384, 64, 512, 1, 0, 0, 0);
  softmax_k<<<16384, 256, 0, stream>>>(SC2, nullptr, 0, 64, 1, 0.125f);
  btrans<ushortT><<<dim3(16, 2, 16), dim3(32, 8), 0, stream>>>(A1S, SAT, 64, 512, lookup);
  gemm(SC2, SAT, QB, nullptr, 0, false, 1024, 512, 64, 16, 64 * 1024, 512 * 64, SD);

  // 6. final gate + output (f32 out: [out(8388608) | gate(16384)])
  float* outp = (float*)d_out;
  final_k<<<16384, 256, 0, stream>>>(XB, QB, post_dec, W_u1, W_u2, b_u1, b_u2, b1,
                                     outp, outp + 8388608);
}

// Round 4
// 1323.067 us; speedup vs baseline: 1.4036x; 1.4036x over previous
//
#include <hip/hip_runtime.h>
#include <hip/hip_bf16.h>
#include <math.h>

typedef __attribute__((ext_vector_type(8))) short short8;
typedef __attribute__((ext_vector_type(4))) float f32x4;
typedef unsigned short ushortT;

// ---------- helpers ----------
__device__ __forceinline__ unsigned short f2b(float f) {
  union { float f; unsigned u; } v; v.f = f;
  return (unsigned short)((v.u + 0x7FFFu + ((v.u >> 16) & 1u)) >> 16);
}
__device__ __forceinline__ float b2f(unsigned short h) {
  union { unsigned u; float f; } v; v.u = ((unsigned)h) << 16;
  return v.f;
}
__device__ __forceinline__ float gelu_f(float x) {
  return 0.5f * x * (1.0f + tanhf(0.7978845608028654f * (x + 0.044715f * x * x * x)));
}
__device__ __forceinline__ float cvt_in(float x) { return x; }
__device__ __forceinline__ float cvt_in(unsigned short x) { return b2f(x); }

// async 16B global -> LDS (DMA, no VGPR round trip). LDS dest = base + lane*16.
__device__ __forceinline__ void async16(ushortT* lds, const ushortT* g) {
  __builtin_amdgcn_global_load_lds(
      (const __attribute__((address_space(1))) void*)g,
      (__attribute__((address_space(3))) void*)lds, 16, 0, 0);
}

// ---------- fast GEMM: C(M,N) = A(M,K) @ Bt(N,K)^T, bf16, f32 acc ----------
// 128x128 tile, BK=64, global_load_lds staging with XOR-swizzled LDS columns.
// REQUIRES: M,N multiples of 128; K multiple of 64; lda/ldb multiples of 8.
// bmode: 0=none, 1=bias[col] (f32), 2=bias[row] (f32)
template<bool GELU>
__global__ __launch_bounds__(256)
void gemm_f(const ushortT* __restrict__ A, const ushortT* __restrict__ Bt,
            ushortT* __restrict__ C, const float* __restrict__ bias, int bmode,
            int K, int lda, int ldb, int ldc,
            long sA, long sB, long sC)
{
  __shared__ ushortT lA[128 * 64];   // row-major, 64 elems (=128B) per row, no pad
  __shared__ ushortT lB[128 * 64];   // LDS[row][cb] holds global[row][cb ^ (row&7)]
  const int z = blockIdx.z;
  A += (long)z * sA;
  Bt += (long)z * sB;
  const long coff = (long)z * sC;
  const int bm = blockIdx.y * 128, bn = blockIdx.x * 128;
  const int tid = threadIdx.x, wave = tid >> 6, lane = tid & 63;
  const int wm = (wave >> 1) << 6, wn = (wave & 1) << 6;
  const int l15 = lane & 15, quad = lane >> 4;

  // staging: chunk c = wave*4+p covers tile rows 4c..4c+3 (1024B each);
  // lane writes LDS colblock (lane&7) of row 4c+(lane>>3); source colblock XOR-swizzled.
  const ushortT* gA[4]; const ushortT* gB[4];
#pragma unroll
  for (int p = 0; p < 4; ++p) {
    int r = 16 * wave + 4 * p + (lane >> 3);
    int sw = (((lane & 7) ^ (r & 7)) << 3);
    gA[p] = A + (long)(bm + r) * lda + sw;
    gB[p] = Bt + (long)(bn + r) * ldb + sw;
  }

  f32x4 acc[4][4];
#pragma unroll
  for (int i = 0; i < 4; ++i)
#pragma unroll
    for (int j = 0; j < 4; ++j) acc[i][j] = (f32x4){0.f, 0.f, 0.f, 0.f};

  const int x0 = l15 & 7;
  for (int k0 = 0; k0 < K; k0 += 64) {
#pragma unroll
    for (int p = 0; p < 4; ++p) {
      async16(&lA[(wave * 4 + p) * 512], gA[p] + k0);
      async16(&lB[(wave * 4 + p) * 512], gB[p] + k0);
    }
    __syncthreads();
    short8 a0[4], a1[4], b0[4], b1[4];
#pragma unroll
    for (int t = 0; t < 4; ++t) {
      int ra = (wm + t * 16 + l15) << 6;
      a0[t] = *(const short8*)&lA[ra + (((quad    ) ^ x0) << 3)];
      a1[t] = *(const short8*)&lA[ra + (((quad + 4) ^ x0) << 3)];
      int rb = (wn + t * 16 + l15) << 6;
      b0[t] = *(const short8*)&lB[rb + (((quad    ) ^ x0) << 3)];
      b1[t] = *(const short8*)&lB[rb + (((quad + 4) ^ x0) << 3)];
    }
#pragma unroll
    for (int i = 0; i < 4; ++i)
#pragma unroll
      for (int j = 0; j < 4; ++j)
        acc[i][j] = __builtin_amdgcn_mfma_f32_16x16x32_bf16(a0[i], b0[j], acc[i][j], 0, 0, 0);
#pragma unroll
    for (int i = 0; i < 4; ++i)
#pragma unroll
      for (int j = 0; j < 4; ++j)
        acc[i][j] = __builtin_amdgcn_mfma_f32_16x16x32_bf16(a1[i], b1[j], acc[i][j], 0, 0, 0);
    __syncthreads();
  }

#pragma unroll
  for (int j = 0; j < 4; ++j) {
    int col = bn + wn + j * 16 + l15;
    float cbv = (bmode == 1) ? bias[col] : 0.0f;
#pragma unroll
    for (int i = 0; i < 4; ++i) {
      int row0 = bm + wm + i * 16 + (quad << 2);
#pragma unroll
      for (int r = 0; r < 4; ++r) {
        int row = row0 + r;
        float bv = (bmode == 2) ? bias[row] : cbv;
        float v = acc[i][j][r] + bv;
        if (GELU) v = gelu_f(v);
        C[coff + (long)row * ldc + col] = f2b(v);
      }
    }
  }
}

// ---------- batched tiled transpose (z,R,C)->(z,C,R) bf16 out, optional gather ----------
template<typename TIn>
__global__ void btrans(const TIn* __restrict__ in, ushortT* __restrict__ out,
                       int R, int C, long ibs, const int* __restrict__ gather) {
  __shared__ float tile[32][33];
  int z = blockIdx.z;
  long ib = (long)(gather ? gather[z] : z) * ibs;
  long ob = (long)z * (long)R * C;
  int c0 = blockIdx.x << 5, r0 = blockIdx.y << 5;
  int tx = threadIdx.x, ty = threadIdx.y;
#pragma unroll
  for (int dy = 0; dy < 32; dy += 8)
    tile[ty + dy][tx] = cvt_in(in[ib + (long)(r0 + ty + dy) * C + c0 + tx]);
  __syncthreads();
#pragma unroll
  for (int dy = 0; dy < 32; dy += 8)
    out[ob + (long)(c0 + ty + dy) * R + r0 + tx] = f2b(tile[tx][ty + dy]);
}

// ---------- f32 -> bf16 convert ----------
__global__ void conv_f2b(const float4* __restrict__ in, uint2* __restrict__ out, long n4) {
  long i = (long)blockIdx.x * 256 + threadIdx.x;
  if (i >= n4) return;
  float4 v = in[i];
  uint2 r;
  r.x = (unsigned)f2b(v.x) | ((unsigned)f2b(v.y) << 16);
  r.y = (unsigned)f2b(v.z) | ((unsigned)f2b(v.w) << 16);
  out[i] = r;
}

// ---------- softmax bias precompute: mode 1 = log(p), mode 2 = logit(p) ----------
__global__ void bias_prep(const float* __restrict__ p, float* __restrict__ o, int mode, int n) {
  int i = blockIdx.x * 256 + threadIdx.x;
  if (i >= n) return;
  float v = p[i];
  o[i] = (mode == 1) ? __logf(v) : (__logf(v) - log1pf(-v));
}

// ---------- rope sin/cos table: tab[pos][i] = (sin, cos)(pos * 10000^(-2i/512)) ----------
__global__ void rope_tab(float2* __restrict__ t) {
  int pos = blockIdx.x, i = threadIdx.x;
  float inv = __expf(-(float)i * 0.035977892078032f);
  float s, c;
  sincosf((float)pos * inv, &s, &c);
  t[(pos << 8) + i] = make_float2(s, c);
}

// ---------- RoPE: bf16 (rows,512) -> bf16, pos = row % 1024, table-driven ----------
__global__ __launch_bounds__(256)
void rope_k(const unsigned* __restrict__ in, unsigned* __restrict__ out,
            const float2* __restrict__ tab) {
  int row = blockIdx.x, i = threadIdx.x;
  float2 sc = tab[((row & 1023) << 8) + i];
  unsigned u = in[(long)row * 256 + i];
  float x1 = b2f((unsigned short)(u & 0xFFFFu));
  float x2 = b2f((unsigned short)(u >> 16));
  float o1 = x1 * sc.y - x2 * sc.x;
  float o2 = x1 * sc.x + x2 * sc.y;
  out[(long)row * 256 + i] = (unsigned)f2b(o1) | ((unsigned)f2b(o2) << 16);
}

// ---------- in-place softmax, L=1024, precomputed f32 bias, shuffle reductions ----------
__global__ __launch_bounds__(256)
void softmax1024(ushortT* __restrict__ x, const float* __restrict__ bias,
                 int rpb, float scale) {
  __shared__ float sred[8];
  int row = blockIdx.x, tid = threadIdx.x, wave = tid >> 6, lane = tid & 63;
  ushortT* xr = x + (long)row * 1024;
  uint2 u = ((const uint2*)xr)[tid];
  float4 bv = make_float4(0.f, 0.f, 0.f, 0.f);
  if (bias) bv = ((const float4*)(bias + (long)(row / rpb) * 1024))[tid];
  float t0 = b2f((ushortT)(u.x & 0xFFFFu)) * scale + bv.x;
  float t1 = b2f((ushortT)(u.x >> 16)) * scale + bv.y;
  float t2 = b2f((ushortT)(u.y & 0xFFFFu)) * scale + bv.z;
  float t3 = b2f((ushortT)(u.y >> 16)) * scale + bv.w;
  float m = fmaxf(fmaxf(t0, t1), fmaxf(t2, t3));
  for (int o = 32; o; o >>= 1) m = fmaxf(m, __shfl_xor(m, o));
  if (lane == 0) sred[wave] = m;
  __syncthreads();
  m = fmaxf(fmaxf(sred[0], sred[1]), fmaxf(sred[2], sred[3]));
  float e0 = __expf(t0 - m), e1 = __expf(t1 - m), e2 = __expf(t2 - m), e3 = __expf(t3 - m);
  float s = e0 + e1 + e2 + e3;
  for (int o = 32; o; o >>= 1) s += __shfl_xor(s, o);
  if (lane == 0) sred[4 + wave] = s;
  __syncthreads();
  float inv = 1.0f / (sred[4] + sred[5] + sred[6] + sred[7]);
  uint2 r;
  r.x = (unsigned)f2b(e0 * inv) | ((unsigned)f2b(e1 * inv) << 16);
  r.y = (unsigned)f2b(e2 * inv) | ((unsigned)f2b(e3 * inv) << 16);
  ((uint2*)xr)[tid] = r;
}

// ---------- in-place softmax, L=64 (one wave per row, 4 rows/block) ----------
__global__ __launch_bounds__(256)
void softmax64(ushortT* __restrict__ x, float scale, int ldr) {
  int row = blockIdx.x * 4 + (threadIdx.x >> 6), lane = threadIdx.x & 63;
  ushortT* xr = x + (long)row * ldr;
  float t = b2f(xr[lane]) * scale;
  float m = t;
  for (int o = 32; o; o >>= 1) m = fmaxf(m, __shfl_xor(m, o));
  float e = __expf(t - m), s = e;
  for (int o = 32; o; o >>= 1) s += __shfl_xor(s, o);
  xr[lane] = f2b(e / s);
}

// ---------- fused residual + LayerNorm on bf16 state (D=512), 1 barrier ----------
__global__ __launch_bounds__(256)
void ln_k(ushortT* __restrict__ xb, const ushortT* __restrict__ res,
          const float* __restrict__ gamma, const float* __restrict__ beta) {
  __shared__ float2 sred[4];
  int row = blockIdx.x, tid = threadIdx.x, wave = tid >> 6, lane = tid & 63;
  long off = (long)row * 512;
  float a = b2f(xb[off + tid]) + b2f(res[off + tid]);
  float b = b2f(xb[off + tid + 256]) + b2f(res[off + tid + 256]);
  float s = a + b, q = a * a + b * b;
  for (int o = 32; o; o >>= 1) { s += __shfl_xor(s, o); q += __shfl_xor(q, o); }
  if (lane == 0) sred[wave] = make_float2(s, q);
  __syncthreads();
  float ts = sred[0].x + sred[1].x + sred[2].x + sred[3].x;
  float tq = sred[0].y + sred[1].y + sred[2].y + sred[3].y;
  float mean = ts * (1.0f / 512.0f);
  float var = tq * (1.0f / 512.0f) - mean * mean;
  float rstd = rsqrtf(fmaxf(var, 0.f) + 1e-5f);
  xb[off + tid]       = f2b((a - mean) * rstd * gamma[tid]       + beta[tid]);
  xb[off + tid + 256] = f2b((b - mean) * rstd * gamma[tid + 256] + beta[tid + 256]);
}

// ---------- v = raw * sigmoid(for_ignore @ W_ig + b_ig), bf16 out ----------
__global__ __launch_bounds__(256)
void gatev_k(const ushortT* __restrict__ fi, const float* __restrict__ raw,
             const float* __restrict__ wig, const float* __restrict__ big,
             ushortT* __restrict__ vout) {
  __shared__ float sred[4];
  int row = blockIdx.x, tid = threadIdx.x, wave = tid >> 6, lane = tid & 63;
  long off = (long)row * 512;
  float d = b2f(fi[off + tid]) * wig[tid] + b2f(fi[off + tid + 256]) * wig[tid + 256];
  for (int o = 32; o; o >>= 1) d += __shfl_xor(d, o);
  if (lane == 0) sred[wave] = d;
  __syncthreads();
  float g = 1.0f / (1.0f + __expf(-(sred[0] + sred[1] + sred[2] + sred[3] + big[0])));
  vout[off + tid]       = f2b(raw[off + tid] * g);
  vout[off + tid + 256] = f2b(raw[off + tid + 256] * g);
}

// ---------- final gating + output write (f32 out) ----------
__global__ __launch_bounds__(256)
void final_k(const ushortT* __restrict__ fu, const ushortT* __restrict__ A2,
             const float* __restrict__ pd, const float* __restrict__ wu1,
             const float* __restrict__ wu2, const float* __restrict__ bu1,
             const float* __restrict__ bu2, const float* __restrict__ b1p,
             float* __restrict__ outx, float* __restrict__ outg) {
  __shared__ float2 sred[4];
  int row = blockIdx.x, tid = threadIdx.x, wave = tid >> 6, lane = tid & 63;
  long off = (long)row * 512;
  float a2a = b2f(A2[off + tid]), a2b = b2f(A2[off + tid + 256]);
  float d1 = b2f(fu[off + tid]) * wu1[tid] + b2f(fu[off + tid + 256]) * wu1[tid + 256];
  float d2 = a2a * wu2[tid] + a2b * wu2[tid + 256];
  for (int o = 32; o; o >>= 1) { d1 += __shfl_xor(d1, o); d2 += __shfl_xor(d2, o); }
  if (lane == 0) sred[wave] = make_float2(d1, d2);
  __syncthreads();
  float t1 = sred[0].x + sred[1].x + sred[2].x + sred[3].x;
  float t2 = sred[0].y + sred[1].y + sred[2].y + sred[3].y;
  float g = 1.0f / (1.0f + __expf(-(t1 + t2 + bu1[0] + bu2[0] + b1p[0] - 4.0f)));
  outx[off + tid]       = pd[off + tid] * (1.0f - g) + a2a * g;
  outx[off + tid + 256] = pd[off + tid + 256] * (1.0f - g) + a2b * g;
  if (tid == 0) outg[row] = g;
}

// ================= host orchestration =================
extern "C" void kernel_launch(void* const* d_in, const int* in_sizes, int n_in,
                              void* d_out, int out_size, void* d_ws, size_t ws_size,
                              hipStream_t stream)
{
  const float* raw_emb = (const float*)d_in[0];
  const float* rpw     = (const float*)d_in[1];
  const float* post_dec= (const float*)d_in[2];
  const float* rpr     = (const float*)d_in[3];
  const float* questions=(const float*)d_in[4];
  const float* W_k  = (const float*)d_in[5];
  const float* W_ig = (const float*)d_in[6];
  const float* b_ig = (const float*)d_in[7];
  const float* W_u1 = (const float*)d_in[8];
  const float* b_u1 = (const float*)d_in[9];
  const float* W_u2 = (const float*)d_in[10];
  const float* b_u2 = (const float*)d_in[11];
  const float* b1   = (const float*)d_in[12];
  const float* W_ok = (const float*)d_in[13];
  const float* b_ok = (const float*)d_in[14];
  const float* ew_qkv = (const float*)d_in[15];
  const float* ew_bqkv= (const float*)d_in[16];
  const float* ew_wo  = (const float*)d_in[17];
  const float* ew_bo  = (const float*)d_in[18];
  const float* ew_ln  = (const float*)d_in[19];
  const float* ew_wff = (const float*)d_in[20];
  const float* ew_bff = (const float*)d_in[21];
  const float* er_qkv = (const float*)d_in[22];
  const float* er_bqkv= (const float*)d_in[23];
  const float* er_wo  = (const float*)d_in[24];
  const float* er_bo  = (const float*)d_in[25];
  const float* er_ln  = (const float*)d_in[26];
  const float* er_wff = (const float*)d_in[27];
  const float* er_bff = (const float*)d_in[28];
  const int* lookup   = (const int*)d_in[29];

  const size_t MAT = 512ull * 512ull;
  const long SD = 1024 * 512;
  char* wsb = (char*)d_ws;
  size_t off = 0;
  auto alloc = [&](size_t b) { char* p = wsb + off; off = (off + b + 255) & ~(size_t)255; return p; };

  ushortT* WT  = (ushortT*)alloc(26 * MAT * 2);             // transposed bf16 weights
  ushortT* XB  = (ushortT*)alloc(16384ull * 512 * 2);       // encoder state
  ushortT* B1  = (ushortT*)alloc(16384ull * 512 * 2);       // pre-rope q/k, o2, f2, vg
  ushortT* SC  = (ushortT*)alloc(16ull * 1024 * 1024 * 2);  // scores/probs (full 16 batches)
  ushortT* QB  = (ushortT*)alloc(16384ull * 512 * 2);       // q / attn-out / A2
  ushortT* KB  = (ushortT*)alloc(16384ull * 512 * 2);       // k / f1
  ushortT* VT  = (ushortT*)alloc(16384ull * 512 * 2);       // V^T / vg^T
  ushortT* K2  = (ushortT*)alloc(16384ull * 512 * 2);       // k2
  ushortT* KD  = (ushortT*)alloc(8192ull * 512 * 2);        // k_docs
  ushortT* QSB = (ushortT*)alloc(128ull * 512 * 2);         // questions bf16 (padded to 128 rows)
  ushortT* SC2 = (ushortT*)alloc(16384ull * 128 * 2);       // A1 scores (8,128,1024) / a2 (16384,128)
  ushortT* A1S = (ushortT*)alloc(8ull * 128 * 512 * 2);     // A1s (padded rows)
  ushortT* SAT = (ushortT*)alloc(16ull * 512 * 64 * 2);     // selA^T
  float*   PBW = (float*)alloc(8192 * 4);                   // log(rpw)
  float*   PBR = (float*)alloc(16384 * 4);                  // logit(rpr)
  float2*  TAB = (float2*)alloc(1024 * 256 * 8);            // rope sin/cos

  auto gemm = [&](const ushortT* A, const ushortT* Bt, ushortT* C, const float* bias,
                  int bmode, bool gelu, int M, int N, int K,
                  int lda, int ldb, int ldc, int Z, long sA, long sB, long sC) {
    dim3 g(N / 128, M / 128, Z);
    if (gelu) gemm_f<true ><<<g, dim3(256), 0, stream>>>(A, Bt, C, bias, bmode, K, lda, ldb, ldc, sA, sB, sC);
    else      gemm_f<false><<<g, dim3(256), 0, stream>>>(A, Bt, C, bias, bmode, K, lda, ldb, ldc, sA, sB, sC);
  };
  auto tw = [&](const float* src, ushortT* dst, int nm) {
    btrans<float><<<dim3(16, 16, nm), dim3(32, 8), 0, stream>>>(src, dst, 512, 512, (long)MAT, nullptr);
  };
  auto conv = [&](const float* src, ushortT* dst, long n) {
    long n4 = n / 4;
    conv_f2b<<<(unsigned)((n4 + 255) / 256), 256, 0, stream>>>((const float4*)src, (uint2*)dst, n4);
  };

  const float isc512 = 0.044194173824159216f; // 1/sqrt(512)

  // 0. precompute: softmax biases, rope table, weight transposes, questions
  bias_prep<<<32, 256, 0, stream>>>(rpw, PBW, 1, 8192);
  bias_prep<<<64, 256, 0, stream>>>(rpr, PBR, 2, 16384);
  rope_tab<<<1024, 256, 0, stream>>>(TAB);
  tw(W_k,    WT + 0 * MAT, 1);
  tw(W_ok,   WT + 1 * MAT, 1);
  tw(ew_qkv, WT + 2 * MAT, 6);
  tw(ew_wo,  WT + 8 * MAT, 2);
  tw(ew_wff, WT + 10 * MAT, 4);
  tw(er_qkv, WT + 14 * MAT, 6);
  tw(er_wo,  WT + 20 * MAT, 2);
  tw(er_wff, WT + 22 * MAT, 4);
  conv(questions, QSB, 64 * 512);   // rows 64..127 stay poison (finite bf16) - never read

  // encoder driver: XB holds bf16(x_in) on entry; leaves XB = encoder output
  auto run_enc = [&](int NB, const ushortT* wqkvT, const float* bqkv,
                     const ushortT* woT, const float* bo, const float* lnp,
                     const ushortT* wffT, const float* bff, const float* pbias) {
    int Mt = NB * 1024;
    for (int l = 0; l < 2; ++l) {
      const ushortT* Wq  = wqkvT + (size_t)(l * 3 + 0) * MAT;
      const ushortT* Wk2 = wqkvT + (size_t)(l * 3 + 1) * MAT;
      const ushortT* Wv  = wqkvT + (size_t)(l * 3 + 2) * MAT;
      gemm(XB, Wq, B1, bqkv + (l * 3 + 0) * 512, 1, false, Mt, 512, 512, 512, 512, 512, 1, 0, 0, 0);
      rope_k<<<Mt, 256, 0, stream>>>((const unsigned*)B1, (unsigned*)QB, TAB);
      gemm(XB, Wk2, B1, bqkv + (l * 3 + 1) * 512, 1, false, Mt, 512, 512, 512, 512, 512, 1, 0, 0, 0);
      rope_k<<<Mt, 256, 0, stream>>>((const unsigned*)B1, (unsigned*)KB, TAB);
      // V^T: C(z,512,1024) = Wv^T @ X^T, bias per row (= output dim)
      gemm(Wv, XB, VT, bqkv + (l * 3 + 2) * 512, 2, false, 512, 1024, 512, 512, 512, 1024, NB, 0, SD, SD);
      gemm(QB, KB, SC, nullptr, 0, false, 1024, 1024, 512, 512, 512, 1024, NB, SD, SD, 1024 * 1024);
      softmax1024<<<Mt, 256, 0, stream>>>(SC, pbias, 1024, isc512);
      gemm(SC, VT, QB, nullptr, 0, false, 1024, 512, 1024, 1024, 1024, 512, NB, 1024 * 1024, SD, SD);
      gemm(QB, woT + (size_t)l * MAT, B1, bo + l * 512, 1, false, Mt, 512, 512, 512, 512, 512, 1, 0, 0, 0);
      ln_k<<<Mt, 256, 0, stream>>>(XB, B1, lnp + (l * 4 + 0) * 512, lnp + (l * 4 + 1) * 512);
      gemm(XB, wffT + (size_t)(l * 2 + 0) * MAT, KB, bff + (l * 2 + 0) * 512, 1, true,
           Mt, 512, 512, 512, 512, 512, 1, 0, 0, 0);
      gemm(KB, wffT + (size_t)(l * 2 + 1) * MAT, B1, bff + (l * 2 + 1) * 512, 1, false,
           Mt, 512, 512, 512, 512, 512, 1, 0, 0, 0);
      ln_k<<<Mt, 256, 0, stream>>>(XB, B1, lnp + (l * 4 + 2) * 512, lnp + (l * 4 + 3) * 512);
    }
  };

  // 1. k_docs = raw_emb @ W_k ; encw -> XB = for_ignore
  conv(raw_emb, XB, 8192ull * 512);
  gemm(XB, WT + 0 * MAT, KD, nullptr, 0, false, 8192, 512, 512, 512, 512, 512, 1, 0, 0, 0);
  run_enc(8, WT + 2 * MAT, ew_bqkv, WT + 8 * MAT, ew_bo, ew_ln, WT + 10 * MAT, ew_bff, PBW);

  // 2. v_gate, A1s (M padded to 128; rows 64..127 garbage, never read downstream)
  gatev_k<<<8192, 256, 0, stream>>>(XB, raw_emb, W_ig, b_ig, B1);
  btrans<ushortT><<<dim3(16, 32, 8), dim3(32, 8), 0, stream>>>(B1, VT, 1024, 512, SD, nullptr);
  gemm(QSB, KD, SC2, nullptr, 0, false, 128, 1024, 512, 512, 512, 1024, 8, 0, SD, 128 * 1024);
  softmax1024<<<1024, 256, 0, stream>>>(SC2, PBW, 128, isc512);
  gemm(SC2, VT, A1S, nullptr, 0, false, 128, 512, 1024, 1024, 1024, 512, 8, 128 * 1024, SD, 128 * 512);

  // 3. k2 (before encr mutates XB), then encr -> XB = for_update
  conv(post_dec, XB, 16384ull * 512);
  gemm(XB, WT + 1 * MAT, K2, b_ok, 1, false, 16384, 512, 512, 512, 512, 512, 1, 0, 0, 0);
  run_enc(16, WT + 14 * MAT, er_bqkv, WT + 20 * MAT, er_bo, er_ln, WT + 22 * MAT, er_bff, PBR);

  // 4. a2 (N padded to 128), A2
  gemm(K2, QSB, SC2, nullptr, 0, false, 16384, 128, 512, 512, 512, 128, 1, 0, 0, 0);
  softmax64<<<4096, 256, 0, stream>>>(SC2, 0.125f, 128);
  btrans<ushortT><<<dim3(16, 2, 16), dim3(32, 8), 0, stream>>>(A1S, SAT, 64, 512, 128 * 512, lookup);
  gemm(SC2, SAT, QB, nullptr, 0, false, 1024, 512, 64, 128, 64, 512, 16, 1024 * 128, 512 * 64, SD);

  // 5. final gate + output (f32 out: [out(8388608) | gate(16384)])
  float* outp = (float*)d_out;
  final_k<<<16384, 256, 0, stream>>>(XB, QB, post_dec, W_u1, W_u2, b_u1, b_u2, b1,
                                     outp, outp + 8388608);
}

// Round 5
// 1258.443 us; speedup vs baseline: 1.4757x; 1.0514x over previous
//
#include <hip/hip_runtime.h>
#include <hip/hip_bf16.h>
#include <math.h>

typedef __attribute__((ext_vector_type(8))) short short8;
typedef __attribute__((ext_vector_type(4))) float f32x4;
typedef unsigned short ushortT;

// ---------- helpers ----------
__device__ __forceinline__ unsigned short f2b(float f) {
  union { float f; unsigned u; } v; v.f = f;
  return (unsigned short)((v.u + 0x7FFFu + ((v.u >> 16) & 1u)) >> 16);
}
__device__ __forceinline__ float b2f(unsigned short h) {
  union { unsigned u; float f; } v; v.u = ((unsigned)h) << 16;
  return v.f;
}
__device__ __forceinline__ float gelu_f(float x) {
  return 0.5f * x * (1.0f + tanhf(0.7978845608028654f * (x + 0.044715f * x * x * x)));
}
__device__ __forceinline__ float cvt_in(float x) { return x; }
__device__ __forceinline__ float cvt_in(unsigned short x) { return b2f(x); }

// async 16B global -> LDS DMA. LDS dest = wave-uniform base + lane*16.
__device__ __forceinline__ void async16(ushortT* lds, const ushortT* g) {
  __builtin_amdgcn_global_load_lds(
      (const __attribute__((address_space(1))) void*)g,
      (__attribute__((address_space(3))) void*)lds, 16, 0, 0);
}

// ---------- GEMM: C(M,N) = A(M,K) @ Bt(N,K)^T, bf16 in/out, f32 acc ----------
// 128x128 tile, BK=32, double-buffered async LDS staging, XOR-swizzled columns.
// REQUIRES: M,N multiples of 128; K multiple of 32; lda/ldb multiples of 8.
// bmode: 0=none, 1=bias[col] (f32), 2=bias[row] (f32)
template<bool GELU>
__global__ __launch_bounds__(256, 4)
void gemm_f(const ushortT* __restrict__ A, const ushortT* __restrict__ Bt,
            ushortT* __restrict__ C, const float* __restrict__ bias, int bmode,
            int K, int lda, int ldb, int ldc,
            long sA, long sB, long sC)
{
  // [buf][A=0/B=1][128 rows * 32 elems]; row = 64B, col-chunks of 8 elems (16B)
  // LDS[row][cb] holds global[row][cb ^ (row&3)]
  __shared__ ushortT lds[2][2][128 * 32];
  const int z = blockIdx.z;
  A += (long)z * sA;
  Bt += (long)z * sB;
  const long coff = (long)z * sC;
  const int bm = blockIdx.y * 128, bn = blockIdx.x * 128;
  const int tid = threadIdx.x, wave = tid >> 6, lane = tid & 63;
  const int wm = (wave >> 1) << 6, wn = (wave & 1) << 6;
  const int l15 = lane & 15, quad = lane >> 4;

  // staging: chunk q (q=0,1) of this wave covers tile rows 32*wave+16*q .. +15.
  // lane handles row +(lane>>2), col-chunk (lane&3); source col-chunk XOR-swizzled.
  const ushortT* gA[2]; const ushortT* gB[2];
  int lchunk[2];
#pragma unroll
  for (int q = 0; q < 2; ++q) {
    int r = 32 * wave + 16 * q + (lane >> 2);
    int sw = (((lane & 3) ^ (r & 3)) << 3);
    gA[q] = A + (long)(bm + r) * lda + sw;
    gB[q] = Bt + (long)(bn + r) * ldb + sw;
    lchunk[q] = (wave * 2 + q) * 512;   // 512 ushorts = 1KB per chunk
  }

  f32x4 acc[4][4];
#pragma unroll
  for (int i = 0; i < 4; ++i)
#pragma unroll
    for (int j = 0; j < 4; ++j) acc[i][j] = (f32x4){0.f, 0.f, 0.f, 0.f};

  const int x0 = l15 & 3;
  const int nk = K >> 5;

  // prologue: stage tile 0 into buf 0
#pragma unroll
  for (int q = 0; q < 2; ++q) {
    async16(&lds[0][0][lchunk[q]], gA[q]);
    async16(&lds[0][1][lchunk[q]], gB[q]);
  }

  int cur = 0;
  for (int k = 0; k < nk; ++k) {
    __syncthreads();                 // drains vmcnt -> stage(cur) complete
    if (k + 1 < nk) {                // prefetch next tile into other buffer
      int k0 = (k + 1) << 5;
#pragma unroll
      for (int q = 0; q < 2; ++q) {
        async16(&lds[cur ^ 1][0][lchunk[q]], gA[q] + k0);
        async16(&lds[cur ^ 1][1][lchunk[q]], gB[q] + k0);
      }
    }
    short8 aF[4], bF[4];
#pragma unroll
    for (int t = 0; t < 4; ++t) {
      int ra = (wm + t * 16 + l15) << 5;
      aF[t] = *(const short8*)&lds[cur][0][ra + ((quad ^ x0) << 3)];
      int rb = (wn + t * 16 + l15) << 5;
      bF[t] = *(const short8*)&lds[cur][1][rb + ((quad ^ x0) << 3)];
    }
#pragma unroll
    for (int i = 0; i < 4; ++i)
#pragma unroll
      for (int j = 0; j < 4; ++j)
        acc[i][j] = __builtin_amdgcn_mfma_f32_16x16x32_bf16(aF[i], bF[j], acc[i][j], 0, 0, 0);
    cur ^= 1;
  }

#pragma unroll
  for (int j = 0; j < 4; ++j) {
    int col = bn + wn + j * 16 + l15;
    float cbv = (bmode == 1) ? bias[col] : 0.0f;
#pragma unroll
    for (int i = 0; i < 4; ++i) {
      int row0 = bm + wm + i * 16 + (quad << 2);
#pragma unroll
      for (int r = 0; r < 4; ++r) {
        int row = row0 + r;
        float bv = (bmode == 2) ? bias[row] : cbv;
        float v = acc[i][j][r] + bv;
        if (GELU) v = gelu_f(v);
        C[coff + (long)row * ldc + col] = f2b(v);
      }
    }
  }
}

// ---------- batched tiled transpose (z,R,C)->(z,C,R) bf16 out, optional gather ----------
template<typename TIn>
__global__ void btrans(const TIn* __restrict__ in, ushortT* __restrict__ out,
                       int R, int C, long ibs, const int* __restrict__ gather) {
  __shared__ float tile[32][33];
  int z = blockIdx.z;
  long ib = (long)(gather ? gather[z] : z) * ibs;
  long ob = (long)z * (long)R * C;
  int c0 = blockIdx.x << 5, r0 = blockIdx.y << 5;
  int tx = threadIdx.x, ty = threadIdx.y;
#pragma unroll
  for (int dy = 0; dy < 32; dy += 8)
    tile[ty + dy][tx] = cvt_in(in[ib + (long)(r0 + ty + dy) * C + c0 + tx]);
  __syncthreads();
#pragma unroll
  for (int dy = 0; dy < 32; dy += 8)
    out[ob + (long)(c0 + ty + dy) * R + r0 + tx] = f2b(tile[tx][ty + dy]);
}

// ---------- f32 -> bf16 convert ----------
__global__ void conv_f2b(const float4* __restrict__ in, uint2* __restrict__ out, long n4) {
  long i = (long)blockIdx.x * 256 + threadIdx.x;
  if (i >= n4) return;
  float4 v = in[i];
  uint2 r;
  r.x = (unsigned)f2b(v.x) | ((unsigned)f2b(v.y) << 16);
  r.y = (unsigned)f2b(v.z) | ((unsigned)f2b(v.w) << 16);
  out[i] = r;
}

// ---------- softmax bias precompute: mode 1 = log(p), mode 2 = logit(p) ----------
__global__ void bias_prep(const float* __restrict__ p, float* __restrict__ o, int mode, int n) {
  int i = blockIdx.x * 256 + threadIdx.x;
  if (i >= n) return;
  float v = p[i];
  o[i] = (mode == 1) ? __logf(v) : (__logf(v) - log1pf(-v));
}

// ---------- rope sin/cos table: tab[pos][i] = (sin, cos)(pos * 10000^(-2i/512)) ----------
__global__ void rope_tab(float2* __restrict__ t) {
  int pos = blockIdx.x, i = threadIdx.x;
  float inv = __expf(-(float)i * 0.035977892078032f);
  float s, c;
  sincosf((float)pos * inv, &s, &c);
  t[(pos << 8) + i] = make_float2(s, c);
}

// ---------- dual RoPE: in = (rows,1024) bf16 [q|k]; writes q,k (rows,512) ----------
__global__ __launch_bounds__(256)
void rope2_k(const unsigned* __restrict__ in, unsigned* __restrict__ qo,
             unsigned* __restrict__ ko, const float2* __restrict__ tab) {
  int row = blockIdx.x, i = threadIdx.x;
  float2 sc = tab[((row & 1023) << 8) + i];
  long base = (long)row * 512;          // row of 512 uints (=1024 bf16)
  unsigned uq = in[base + i];
  unsigned uk = in[base + 256 + i];
  float q1 = b2f((ushortT)(uq & 0xFFFFu)), q2 = b2f((ushortT)(uq >> 16));
  float k1 = b2f((ushortT)(uk & 0xFFFFu)), k2 = b2f((ushortT)(uk >> 16));
  float qa = q1 * sc.y - q2 * sc.x, qb = q1 * sc.x + q2 * sc.y;
  float ka = k1 * sc.y - k2 * sc.x, kb = k1 * sc.x + k2 * sc.y;
  qo[(long)row * 256 + i] = (unsigned)f2b(qa) | ((unsigned)f2b(qb) << 16);
  ko[(long)row * 256 + i] = (unsigned)f2b(ka) | ((unsigned)f2b(kb) << 16);
}

// ---------- in-place softmax, L=1024, precomputed f32 bias, shuffle reductions ----------
__global__ __launch_bounds__(256)
void softmax1024(ushortT* __restrict__ x, const float* __restrict__ bias,
                 int rpb, float scale) {
  __shared__ float sred[8];
  int row = blockIdx.x, tid = threadIdx.x, wave = tid >> 6, lane = tid & 63;
  ushortT* xr = x + (long)row * 1024;
  uint2 u = ((const uint2*)xr)[tid];
  float4 bv = make_float4(0.f, 0.f, 0.f, 0.f);
  if (bias) bv = ((const float4*)(bias + (long)(row / rpb) * 1024))[tid];
  float t0 = b2f((ushortT)(u.x & 0xFFFFu)) * scale + bv.x;
  float t1 = b2f((ushortT)(u.x >> 16)) * scale + bv.y;
  float t2 = b2f((ushortT)(u.y & 0xFFFFu)) * scale + bv.z;
  float t3 = b2f((ushortT)(u.y >> 16)) * scale + bv.w;
  float m = fmaxf(fmaxf(t0, t1), fmaxf(t2, t3));
  for (int o = 32; o; o >>= 1) m = fmaxf(m, __shfl_xor(m, o));
  if (lane == 0) sred[wave] = m;
  __syncthreads();
  m = fmaxf(fmaxf(sred[0], sred[1]), fmaxf(sred[2], sred[3]));
  float e0 = __expf(t0 - m), e1 = __expf(t1 - m), e2 = __expf(t2 - m), e3 = __expf(t3 - m);
  float s = e0 + e1 + e2 + e3;
  for (int o = 32; o; o >>= 1) s += __shfl_xor(s, o);
  if (lane == 0) sred[4 + wave] = s;
  __syncthreads();
  float inv = 1.0f / (sred[4] + sred[5] + sred[6] + sred[7]);
  uint2 r;
  r.x = (unsigned)f2b(e0 * inv) | ((unsigned)f2b(e1 * inv) << 16);
  r.y = (unsigned)f2b(e2 * inv) | ((unsigned)f2b(e3 * inv) << 16);
  ((uint2*)xr)[tid] = r;
}

// ---------- in-place softmax, L=64 (one wave per row, 4 rows/block) ----------
__global__ __launch_bounds__(256)
void softmax64(ushortT* __restrict__ x, float scale, int ldr) {
  int row = blockIdx.x * 4 + (threadIdx.x >> 6), lane = threadIdx.x & 63;
  ushortT* xr = x + (long)row * ldr;
  float t = b2f(xr[lane]) * scale;
  float m = t;
  for (int o = 32; o; o >>= 1) m = fmaxf(m, __shfl_xor(m, o));
  float e = __expf(t - m), s = e;
  for (int o = 32; o; o >>= 1) s += __shfl_xor(s, o);
  xr[lane] = f2b(e / s);
}

// ---------- fused residual + LayerNorm on bf16 state (D=512), 1 barrier ----------
__global__ __launch_bounds__(256)
void ln_k(ushortT* __restrict__ xb, const ushortT* __restrict__ res,
          const float* __restrict__ gamma, const float* __restrict__ beta) {
  __shared__ float2 sred[4];
  int row = blockIdx.x, tid = threadIdx.x, wave = tid >> 6, lane = tid & 63;
  long off = (long)row * 512;
  float a = b2f(xb[off + tid]) + b2f(res[off + tid]);
  float b = b2f(xb[off + tid + 256]) + b2f(res[off + tid + 256]);
  float s = a + b, q = a * a + b * b;
  for (int o = 32; o; o >>= 1) { s += __shfl_xor(s, o); q += __shfl_xor(q, o); }
  if (lane == 0) sred[wave] = make_float2(s, q);
  __syncthreads();
  float ts = sred[0].x + sred[1].x + sred[2].x + sred[3].x;
  float tq = sred[0].y + sred[1].y + sred[2].y + sred[3].y;
  float mean = ts * (1.0f / 512.0f);
  float var = tq * (1.0f / 512.0f) - mean * mean;
  float rstd = rsqrtf(fmaxf(var, 0.f) + 1e-5f);
  xb[off + tid]       = f2b((a - mean) * rstd * gamma[tid]       + beta[tid]);
  xb[off + tid + 256] = f2b((b - mean) * rstd * gamma[tid + 256] + beta[tid + 256]);
}

// ---------- v = raw * sigmoid(for_ignore @ W_ig + b_ig), bf16 out ----------
__global__ __launch_bounds__(256)
void gatev_k(const ushortT* __restrict__ fi, const float* __restrict__ raw,
             const float* __restrict__ wig, const float* __restrict__ big,
             ushortT* __restrict__ vout) {
  __shared__ float sred[4];
  int row = blockIdx.x, tid = threadIdx.x, wave = tid >> 6, lane = tid & 63;
  long off = (long)row * 512;
  float d = b2f(fi[off + tid]) * wig[tid] + b2f(fi[off + tid + 256]) * wig[tid + 256];
  for (int o = 32; o; o >>= 1) d += __shfl_xor(d, o);
  if (lane == 0) sred[wave] = d;
  __syncthreads();
  float g = 1.0f / (1.0f + __expf(-(sred[0] + sred[1] + sred[2] + sred[3] + big[0])));
  vout[off + tid]       = f2b(raw[off + tid] * g);
  vout[off + tid + 256] = f2b(raw[off + tid + 256] * g);
}

// ---------- final gating + output write (f32 out) ----------
__global__ __launch_bounds__(256)
void final_k(const ushortT* __restrict__ fu, const ushortT* __restrict__ A2,
             const float* __restrict__ pd, const float* __restrict__ wu1,
             const float* __restrict__ wu2, const float* __restrict__ bu1,
             const float* __restrict__ bu2, const float* __restrict__ b1p,
             float* __restrict__ outx, float* __restrict__ outg) {
  __shared__ float2 sred[4];
  int row = blockIdx.x, tid = threadIdx.x, wave = tid >> 6, lane = tid & 63;
  long off = (long)row * 512;
  float a2a = b2f(A2[off + tid]), a2b = b2f(A2[off + tid + 256]);
  float d1 = b2f(fu[off + tid]) * wu1[tid] + b2f(fu[off + tid + 256]) * wu1[tid + 256];
  float d2 = a2a * wu2[tid] + a2b * wu2[tid + 256];
  for (int o = 32; o; o >>= 1) { d1 += __shfl_xor(d1, o); d2 += __shfl_xor(d2, o); }
  if (lane == 0) sred[wave] = make_float2(d1, d2);
  __syncthreads();
  float t1 = sred[0].x + sred[1].x + sred[2].x + sred[3].x;
  float t2 = sred[0].y + sred[1].y + sred[2].y + sred[3].y;
  float g = 1.0f / (1.0f + __expf(-(t1 + t2 + bu1[0] + bu2[0] + b1p[0] - 4.0f)));
  outx[off + tid]       = pd[off + tid] * (1.0f - g) + a2a * g;
  outx[off + tid + 256] = pd[off + tid + 256] * (1.0f - g) + a2b * g;
  if (tid == 0) outg[row] = g;
}

// ================= host orchestration =================
extern "C" void kernel_launch(void* const* d_in, const int* in_sizes, int n_in,
                              void* d_out, int out_size, void* d_ws, size_t ws_size,
                              hipStream_t stream)
{
  const float* raw_emb = (const float*)d_in[0];
  const float* rpw     = (const float*)d_in[1];
  const float* post_dec= (const float*)d_in[2];
  const float* rpr     = (const float*)d_in[3];
  const float* questions=(const float*)d_in[4];
  const float* W_k  = (const float*)d_in[5];
  const float* W_ig = (const float*)d_in[6];
  const float* b_ig = (const float*)d_in[7];
  const float* W_u1 = (const float*)d_in[8];
  const float* b_u1 = (const float*)d_in[9];
  const float* W_u2 = (const float*)d_in[10];
  const float* b_u2 = (const float*)d_in[11];
  const float* b1   = (const float*)d_in[12];
  const float* W_ok = (const float*)d_in[13];
  const float* b_ok = (const float*)d_in[14];
  const float* ew_qkv = (const float*)d_in[15];
  const float* ew_bqkv= (const float*)d_in[16];
  const float* ew_wo  = (const float*)d_in[17];
  const float* ew_bo  = (const float*)d_in[18];
  const float* ew_ln  = (const float*)d_in[19];
  const float* ew_wff = (const float*)d_in[20];
  const float* ew_bff = (const float*)d_in[21];
  const float* er_qkv = (const float*)d_in[22];
  const float* er_bqkv= (const float*)d_in[23];
  const float* er_wo  = (const float*)d_in[24];
  const float* er_bo  = (const float*)d_in[25];
  const float* er_ln  = (const float*)d_in[26];
  const float* er_wff = (const float*)d_in[27];
  const float* er_bff = (const float*)d_in[28];
  const int* lookup   = (const int*)d_in[29];

  const size_t MAT = 512ull * 512ull;
  const long SD = 1024 * 512;
  char* wsb = (char*)d_ws;
  size_t off = 0;
  auto alloc = [&](size_t b) { char* p = wsb + off; off = (off + b + 255) & ~(size_t)255; return p; };

  ushortT* WT  = (ushortT*)alloc(26 * MAT * 2);             // transposed bf16 weights
  ushortT* XB  = (ushortT*)alloc(16384ull * 512 * 2);       // encoder state
  ushortT* B1  = (ushortT*)alloc(16384ull * 1024 * 2);      // [q|k] pre-rope / o2 / f2 / vg
  ushortT* SC  = (ushortT*)alloc(16ull * 1024 * 1024 * 2);  // scores/probs
  ushortT* QB  = (ushortT*)alloc(16384ull * 512 * 2);       // q / attn-out / A2
  ushortT* KB  = (ushortT*)alloc(16384ull * 512 * 2);       // k / f1
  ushortT* VT  = (ushortT*)alloc(16384ull * 512 * 2);       // V^T / vg^T
  ushortT* K2  = (ushortT*)alloc(16384ull * 512 * 2);       // k2
  ushortT* KD  = (ushortT*)alloc(8192ull * 512 * 2);        // k_docs
  ushortT* QSB = (ushortT*)alloc(128ull * 512 * 2);         // questions bf16 (padded)
  ushortT* SC2 = (ushortT*)alloc(16384ull * 128 * 2);       // A1 scores / a2 logits
  ushortT* A1S = (ushortT*)alloc(8ull * 128 * 512 * 2);     // A1s (padded rows)
  ushortT* SAT = (ushortT*)alloc(16ull * 512 * 64 * 2);     // selA^T
  float*   PBW = (float*)alloc(8192 * 4);                   // log(rpw)
  float*   PBR = (float*)alloc(16384 * 4);                  // logit(rpr)
  float2*  TAB = (float2*)alloc(1024 * 256 * 8);            // rope sin/cos

  auto gemm = [&](const ushortT* A, const ushortT* Bt, ushortT* C, const float* bias,
                  int bmode, bool gelu, int M, int N, int K,
                  int lda, int ldb, int ldc, int Z, long sA, long sB, long sC) {
    dim3 g(N / 128, M / 128, Z);
    if (gelu) gemm_f<true ><<<g, dim3(256), 0, stream>>>(A, Bt, C, bias, bmode, K, lda, ldb, ldc, sA, sB, sC);
    else      gemm_f<false><<<g, dim3(256), 0, stream>>>(A, Bt, C, bias, bmode, K, lda, ldb, ldc, sA, sB, sC);
  };
  auto tw = [&](const float* src, ushortT* dst, int nm) {
    btrans<float><<<dim3(16, 16, nm), dim3(32, 8), 0, stream>>>(src, dst, 512, 512, (long)MAT, nullptr);
  };
  auto conv = [&](const float* src, ushortT* dst, long n) {
    long n4 = n / 4;
    conv_f2b<<<(unsigned)((n4 + 255) / 256), 256, 0, stream>>>((const float4*)src, (uint2*)dst, n4);
  };

  const float isc512 = 0.044194173824159216f; // 1/sqrt(512)

  // 0. precompute
  bias_prep<<<32, 256, 0, stream>>>(rpw, PBW, 1, 8192);
  bias_prep<<<64, 256, 0, stream>>>(rpr, PBR, 2, 16384);
  rope_tab<<<1024, 256, 0, stream>>>(TAB);
  tw(W_k,    WT + 0 * MAT, 1);
  tw(W_ok,   WT + 1 * MAT, 1);
  tw(ew_qkv, WT + 2 * MAT, 6);
  tw(ew_wo,  WT + 8 * MAT, 2);
  tw(ew_wff, WT + 10 * MAT, 4);
  tw(er_qkv, WT + 14 * MAT, 6);
  tw(er_wo,  WT + 20 * MAT, 2);
  tw(er_wff, WT + 22 * MAT, 4);
  conv(questions, QSB, 64 * 512);   // rows 64..127 stay poison (finite) - never used

  // encoder driver: XB holds bf16(x_in) on entry; leaves XB = encoder output
  auto run_enc = [&](int NB, const ushortT* wqkvT, const float* bqkv,
                     const ushortT* woT, const float* bo, const float* lnp,
                     const ushortT* wffT, const float* bff, const float* pbias) {
    int Mt = NB * 1024;
    for (int l = 0; l < 2; ++l) {
      const ushortT* Wqk = wqkvT + (size_t)(l * 3 + 0) * MAT;  // [Wq^T ; Wk^T] = (1024,512)
      const ushortT* Wv  = wqkvT + (size_t)(l * 3 + 2) * MAT;
      // fused q|k projection: C = (Mt,1024), bias = [bq ; bk] contiguous
      gemm(XB, Wqk, B1, bqkv + (l * 3 + 0) * 512, 1, false, Mt, 1024, 512, 512, 512, 1024, 1, 0, 0, 0);
      rope2_k<<<Mt, 256, 0, stream>>>((const unsigned*)B1, (unsigned*)QB, (unsigned*)KB, TAB);
      // V^T: C(z,512,1024) = Wv^T @ X^T, bias per row (= output dim)
      gemm(Wv, XB, VT, bqkv + (l * 3 + 2) * 512, 2, false, 512, 1024, 512, 512, 512, 1024, NB, 0, SD, SD);
      gemm(QB, KB, SC, nullptr, 0, false, 1024, 1024, 512, 512, 512, 1024, NB, SD, SD, 1024 * 1024);
      softmax1024<<<Mt, 256, 0, stream>>>(SC, pbias, 1024, isc512);
      gemm(SC, VT, QB, nullptr, 0, false, 1024, 512, 1024, 1024, 1024, 512, NB, 1024 * 1024, SD, SD);
      gemm(QB, woT + (size_t)l * MAT, B1, bo + l * 512, 1, false, Mt, 512, 512, 512, 512, 512, 1, 0, 0, 0);
      ln_k<<<Mt, 256, 0, stream>>>(XB, B1, lnp + (l * 4 + 0) * 512, lnp + (l * 4 + 1) * 512);
      gemm(XB, wffT + (size_t)(l * 2 + 0) * MAT, KB, bff + (l * 2 + 0) * 512, 1, true,
           Mt, 512, 512, 512, 512, 512, 1, 0, 0, 0);
      gemm(KB, wffT + (size_t)(l * 2 + 1) * MAT, B1, bff + (l * 2 + 1) * 512, 1, false,
           Mt, 512, 512, 512, 512, 512, 1, 0, 0, 0);
      ln_k<<<Mt, 256, 0, stream>>>(XB, B1, lnp + (l * 4 + 2) * 512, lnp + (l * 4 + 3) * 512);
    }
  };

  // 1. k_docs = raw_emb @ W_k ; encw -> XB = for_ignore
  conv(raw_emb, XB, 8192ull * 512);
  gemm(XB, WT + 0 * MAT, KD, nullptr, 0, false, 8192, 512, 512, 512, 512, 512, 1, 0, 0, 0);
  run_enc(8, WT + 2 * MAT, ew_bqkv, WT + 8 * MAT, ew_bo, ew_ln, WT + 10 * MAT, ew_bff, PBW);

  // 2. v_gate, A1s (M padded to 128; rows 64..127 garbage, never read downstream)
  gatev_k<<<8192, 256, 0, stream>>>(XB, raw_emb, W_ig, b_ig, B1);
  btrans<ushortT><<<dim3(16, 32, 8), dim3(32, 8), 0, stream>>>(B1, VT, 1024, 512, SD, nullptr);
  gemm(QSB, KD, SC2, nullptr, 0, false, 128, 1024, 512, 512, 512, 1024, 8, 0, SD, 128 * 1024);
  softmax1024<<<1024, 256, 0, stream>>>(SC2, PBW, 128, isc512);
  gemm(SC2, VT, A1S, nullptr, 0, false, 128, 512, 1024, 1024, 1024, 512, 8, 128 * 1024, SD, 128 * 512);

  // 3. k2 (before encr mutates XB), then encr -> XB = for_update
  conv(post_dec, XB, 16384ull * 512);
  gemm(XB, WT + 1 * MAT, K2, b_ok, 1, false, 16384, 512, 512, 512, 512, 512, 1, 0, 0, 0);
  run_enc(16, WT + 14 * MAT, er_bqkv, WT + 20 * MAT, er_bo, er_ln, WT + 22 * MAT, er_bff, PBR);

  // 4. a2 (N padded to 128), A2
  gemm(K2, QSB, SC2, nullptr, 0, false, 16384, 128, 512, 512, 512, 128, 1, 0, 0, 0);
  softmax64<<<4096, 256, 0, stream>>>(SC2, 0.125f, 128);
  btrans<ushortT><<<dim3(16, 2, 16), dim3(32, 8), 0, stream>>>(A1S, SAT, 64, 512, 128 * 512, lookup);
  gemm(SC2, SAT, QB, nullptr, 0, false, 1024, 512, 64, 128, 64, 512, 16, 1024 * 128, 512 * 64, SD);

  // 5. final gate + output (f32 out: [out(8388608) | gate(16384)])
  float* outp = (float*)d_out;
  final_k<<<16384, 256, 0, stream>>>(XB, QB, post_dec, W_u1, W_u2, b_u1, b_u2, b1,
                                     outp, outp + 8388608);
}

// Round 6
// 1071.306 us; speedup vs baseline: 1.7335x; 1.1747x over previous
//
#include <hip/hip_runtime.h>
#include <hip/hip_bf16.h>
#include <math.h>

typedef __attribute__((ext_vector_type(8))) short short8;
typedef __attribute__((ext_vector_type(4))) float f32x4;
typedef unsigned short ushortT;

// ---------- helpers ----------
__device__ __forceinline__ unsigned short f2b(float f) {
  union { float f; unsigned u; } v; v.f = f;
  return (unsigned short)((v.u + 0x7FFFu + ((v.u >> 16) & 1u)) >> 16);
}
__device__ __forceinline__ float b2f(unsigned short h) {
  union { unsigned u; float f; } v; v.u = ((unsigned)h) << 16;
  return v.f;
}
__device__ __forceinline__ float gelu_f(float x) {
  return 0.5f * x * (1.0f + tanhf(0.7978845608028654f * (x + 0.044715f * x * x * x)));
}
__device__ __forceinline__ float cvt_in(float x) { return x; }
__device__ __forceinline__ float cvt_in(unsigned short x) { return b2f(x); }

// async 16B global -> LDS DMA. LDS dest = wave-uniform base + lane*16.
__device__ __forceinline__ void async16(ushortT* lds, const ushortT* g) {
  __builtin_amdgcn_global_load_lds(
      (const __attribute__((address_space(1))) void*)g,
      (__attribute__((address_space(3))) void*)lds, 16, 0, 0);
}

// ---------- GEMM: C(M,N) = A(M,K) @ Bt(N,K)^T, bf16 in/out, f32 acc ----------
// 128x128 tile, BK=32, double-buffered async LDS staging, XOR-swizzled columns
// (s(row) = (row>>1)&3 -> 2-way max on ds_read_b128 = free), LDS-staged
// coalesced C writes (full 128B lines, no L2 read-modify-write).
// REQUIRES: M,N multiples of 128; K multiple of 32; lda/ldb/ldc multiples of 8.
// bmode: 0=none, 1=bias[col] (f32), 2=bias[row] (f32)
template<bool GELU>
__global__ __launch_bounds__(256, 4)
void gemm_f(const ushortT* __restrict__ A, const ushortT* __restrict__ Bt,
            ushortT* __restrict__ C, const float* __restrict__ bias, int bmode,
            int K, int lda, int ldb, int ldc,
            long sA, long sB, long sC)
{
  // [buf][A=0/B=1][128 rows * 32 elems]; reused after k-loop as 128x128 bf16 C-tile
  __shared__ ushortT lds[2][2][128 * 32];
  const int z = blockIdx.z;
  A += (long)z * sA;
  Bt += (long)z * sB;
  const long coff = (long)z * sC;
  const int bm = blockIdx.y * 128, bn = blockIdx.x * 128;
  const int tid = threadIdx.x, wave = tid >> 6, lane = tid & 63;
  const int wm = (wave >> 1) << 6, wn = (wave & 1) << 6;
  const int l15 = lane & 15, quad = lane >> 4;

  // staging: chunk q of this wave covers tile rows 32*wave+16*q .. +15.
  // lane handles row +(lane>>2), LDS col-chunk (lane&3); source chunk XOR-swizzled.
  const ushortT* gA[2]; const ushortT* gB[2];
  int lchunk[2];
#pragma unroll
  for (int q = 0; q < 2; ++q) {
    int r = 32 * wave + 16 * q + (lane >> 2);
    int sw = (((lane & 3) ^ ((r >> 1) & 3)) << 3);
    gA[q] = A + (long)(bm + r) * lda + sw;
    gB[q] = Bt + (long)(bn + r) * ldb + sw;
    lchunk[q] = (wave * 2 + q) * 512;   // 512 ushorts = 1KB per chunk
  }

  f32x4 acc[4][4];
#pragma unroll
  for (int i = 0; i < 4; ++i)
#pragma unroll
    for (int j = 0; j < 4; ++j) acc[i][j] = (f32x4){0.f, 0.f, 0.f, 0.f};

  const int x0 = (l15 >> 1) & 3;       // read-side swizzle: (row>>1)&3 with row=..+l15
  const int nk = K >> 5;

  // prologue: stage tile 0 into buf 0
#pragma unroll
  for (int q = 0; q < 2; ++q) {
    async16(&lds[0][0][lchunk[q]], gA[q]);
    async16(&lds[0][1][lchunk[q]], gB[q]);
  }

  int cur = 0;
  for (int k = 0; k < nk; ++k) {
    __syncthreads();                 // drains vmcnt -> stage(cur) complete
    if (k + 1 < nk) {                // prefetch next tile into other buffer
      int k0 = (k + 1) << 5;
#pragma unroll
      for (int q = 0; q < 2; ++q) {
        async16(&lds[cur ^ 1][0][lchunk[q]], gA[q] + k0);
        async16(&lds[cur ^ 1][1][lchunk[q]], gB[q] + k0);
      }
    }
    short8 aF[4], bF[4];
#pragma unroll
    for (int t = 0; t < 4; ++t) {
      int ra = (wm + t * 16 + l15) << 5;
      aF[t] = *(const short8*)&lds[cur][0][ra + ((quad ^ x0) << 3)];
      int rb = (wn + t * 16 + l15) << 5;
      bF[t] = *(const short8*)&lds[cur][1][rb + ((quad ^ x0) << 3)];
    }
#pragma unroll
    for (int i = 0; i < 4; ++i)
#pragma unroll
      for (int j = 0; j < 4; ++j)
        acc[i][j] = __builtin_amdgcn_mfma_f32_16x16x32_bf16(aF[i], bF[j], acc[i][j], 0, 0, 0);
    cur ^= 1;
  }

  // epilogue: acc -> LDS C-tile (bf16) -> coalesced uint4 global writes
  __syncthreads();
  ushortT* ct = &lds[0][0][0];        // 128*128 bf16 = 32 KB (whole staging array)
#pragma unroll
  for (int j = 0; j < 4; ++j) {
    int tcol = wn + j * 16 + l15;
    float cbv = (bmode == 1) ? bias[bn + tcol] : 0.0f;
#pragma unroll
    for (int i = 0; i < 4; ++i) {
      int row0 = wm + i * 16 + (quad << 2);
#pragma unroll
      for (int r = 0; r < 4; ++r) {
        int row = row0 + r;
        float bv = (bmode == 2) ? bias[bm + row] : cbv;
        float v = acc[i][j][r] + bv;
        if (GELU) v = gelu_f(v);
        ct[(row << 7) + tcol] = f2b(v);
      }
    }
  }
  __syncthreads();
#pragma unroll
  for (int it = 0; it < 8; ++it) {
    int trow = it * 16 + (tid >> 4);
    int tcol = (tid & 15) << 3;
    *(uint4*)&C[coff + (long)(bm + trow) * ldc + bn + tcol] =
        *(const uint4*)&ct[(trow << 7) + tcol];
  }
}

// ---------- batched tiled transpose (z,R,C)->(z,C,R) bf16 out, optional gather ----------
template<typename TIn>
__global__ void btrans(const TIn* __restrict__ in, ushortT* __restrict__ out,
                       int R, int C, long ibs, const int* __restrict__ gather) {
  __shared__ float tile[32][33];
  int z = blockIdx.z;
  long ib = (long)(gather ? gather[z] : z) * ibs;
  long ob = (long)z * (long)R * C;
  int c0 = blockIdx.x << 5, r0 = blockIdx.y << 5;
  int tx = threadIdx.x, ty = threadIdx.y;
#pragma unroll
  for (int dy = 0; dy < 32; dy += 8)
    tile[ty + dy][tx] = cvt_in(in[ib + (long)(r0 + ty + dy) * C + c0 + tx]);
  __syncthreads();
#pragma unroll
  for (int dy = 0; dy < 32; dy += 8)
    out[ob + (long)(c0 + ty + dy) * R + r0 + tx] = f2b(tile[tx][ty + dy]);
}

// ---------- f32 -> bf16 convert ----------
__global__ void conv_f2b(const float4* __restrict__ in, uint2* __restrict__ out, long n4) {
  long i = (long)blockIdx.x * 256 + threadIdx.x;
  if (i >= n4) return;
  float4 v = in[i];
  uint2 r;
  r.x = (unsigned)f2b(v.x) | ((unsigned)f2b(v.y) << 16);
  r.y = (unsigned)f2b(v.z) | ((unsigned)f2b(v.w) << 16);
  out[i] = r;
}

// ---------- softmax bias precompute: mode 1 = log(p), mode 2 = logit(p) ----------
__global__ void bias_prep(const float* __restrict__ p, float* __restrict__ o, int mode, int n) {
  int i = blockIdx.x * 256 + threadIdx.x;
  if (i >= n) return;
  float v = p[i];
  o[i] = (mode == 1) ? __logf(v) : (__logf(v) - log1pf(-v));
}

// ---------- rope sin/cos table: tab[pos][i] = (sin, cos)(pos * 10000^(-2i/512)) ----------
__global__ void rope_tab(float2* __restrict__ t) {
  int pos = blockIdx.x, i = threadIdx.x;
  float inv = __expf(-(float)i * 0.035977892078032f);
  float s, c;
  sincosf((float)pos * inv, &s, &c);
  t[(pos << 8) + i] = make_float2(s, c);
}

// ---------- dual RoPE: in = (rows,1024) bf16 [q|k]; writes q,k (rows,512) ----------
__global__ __launch_bounds__(256)
void rope2_k(const unsigned* __restrict__ in, unsigned* __restrict__ qo,
             unsigned* __restrict__ ko, const float2* __restrict__ tab) {
  int row = blockIdx.x, i = threadIdx.x;
  float2 sc = tab[((row & 1023) << 8) + i];
  long base = (long)row * 512;          // row of 512 uints (=1024 bf16)
  unsigned uq = in[base + i];
  unsigned uk = in[base + 256 + i];
  float q1 = b2f((ushortT)(uq & 0xFFFFu)), q2 = b2f((ushortT)(uq >> 16));
  float k1 = b2f((ushortT)(uk & 0xFFFFu)), k2 = b2f((ushortT)(uk >> 16));
  float qa = q1 * sc.y - q2 * sc.x, qb = q1 * sc.x + q2 * sc.y;
  float ka = k1 * sc.y - k2 * sc.x, kb = k1 * sc.x + k2 * sc.y;
  qo[(long)row * 256 + i] = (unsigned)f2b(qa) | ((unsigned)f2b(qb) << 16);
  ko[(long)row * 256 + i] = (unsigned)f2b(ka) | ((unsigned)f2b(kb) << 16);
}

// ---------- in-place softmax, L=1024, precomputed f32 bias, shuffle reductions ----------
__global__ __launch_bounds__(256)
void softmax1024(ushortT* __restrict__ x, const float* __restrict__ bias,
                 int rpb, float scale) {
  __shared__ float sred[8];
  int row = blockIdx.x, tid = threadIdx.x, wave = tid >> 6, lane = tid & 63;
  ushortT* xr = x + (long)row * 1024;
  uint2 u = ((const uint2*)xr)[tid];
  float4 bv = make_float4(0.f, 0.f, 0.f, 0.f);
  if (bias) bv = ((const float4*)(bias + (long)(row / rpb) * 1024))[tid];
  float t0 = b2f((ushortT)(u.x & 0xFFFFu)) * scale + bv.x;
  float t1 = b2f((ushortT)(u.x >> 16)) * scale + bv.y;
  float t2 = b2f((ushortT)(u.y & 0xFFFFu)) * scale + bv.z;
  float t3 = b2f((ushortT)(u.y >> 16)) * scale + bv.w;
  float m = fmaxf(fmaxf(t0, t1), fmaxf(t2, t3));
  for (int o = 32; o; o >>= 1) m = fmaxf(m, __shfl_xor(m, o));
  if (lane == 0) sred[wave] = m;
  __syncthreads();
  m = fmaxf(fmaxf(sred[0], sred[1]), fmaxf(sred[2], sred[3]));
  float e0 = __expf(t0 - m), e1 = __expf(t1 - m), e2 = __expf(t2 - m), e3 = __expf(t3 - m);
  float s = e0 + e1 + e2 + e3;
  for (int o = 32; o; o >>= 1) s += __shfl_xor(s, o);
  if (lane == 0) sred[4 + wave] = s;
  __syncthreads();
  float inv = 1.0f / (sred[4] + sred[5] + sred[6] + sred[7]);
  uint2 r;
  r.x = (unsigned)f2b(e0 * inv) | ((unsigned)f2b(e1 * inv) << 16);
  r.y = (unsigned)f2b(e2 * inv) | ((unsigned)f2b(e3 * inv) << 16);
  ((uint2*)xr)[tid] = r;
}

// ---------- in-place softmax, L=64 (one wave per row, 4 rows/block) ----------
__global__ __launch_bounds__(256)
void softmax64(ushortT* __restrict__ x, float scale, int ldr) {
  int row = blockIdx.x * 4 + (threadIdx.x >> 6), lane = threadIdx.x & 63;
  ushortT* xr = x + (long)row * ldr;
  float t = b2f(xr[lane]) * scale;
  float m = t;
  for (int o = 32; o; o >>= 1) m = fmaxf(m, __shfl_xor(m, o));
  float e = __expf(t - m), s = e;
  for (int o = 32; o; o >>= 1) s += __shfl_xor(s, o);
  xr[lane] = f2b(e / s);
}

// ---------- fused residual + LayerNorm on bf16 state (D=512), 1 barrier ----------
__global__ __launch_bounds__(256)
void ln_k(ushortT* __restrict__ xb, const ushortT* __restrict__ res,
          const float* __restrict__ gamma, const float* __restrict__ beta) {
  __shared__ float2 sred[4];
  int row = blockIdx.x, tid = threadIdx.x, wave = tid >> 6, lane = tid & 63;
  long off = (long)row * 512;
  float a = b2f(xb[off + tid]) + b2f(res[off + tid]);
  float b = b2f(xb[off + tid + 256]) + b2f(res[off + tid + 256]);
  float s = a + b, q = a * a + b * b;
  for (int o = 32; o; o >>= 1) { s += __shfl_xor(s, o); q += __shfl_xor(q, o); }
  if (lane == 0) sred[wave] = make_float2(s, q);
  __syncthreads();
  float ts = sred[0].x + sred[1].x + sred[2].x + sred[3].x;
  float tq = sred[0].y + sred[1].y + sred[2].y + sred[3].y;
  float mean = ts * (1.0f / 512.0f);
  float var = tq * (1.0f / 512.0f) - mean * mean;
  float rstd = rsqrtf(fmaxf(var, 0.f) + 1e-5f);
  xb[off + tid]       = f2b((a - mean) * rstd * gamma[tid]       + beta[tid]);
  xb[off + tid + 256] = f2b((b - mean) * rstd * gamma[tid + 256] + beta[tid + 256]);
}

// ---------- v = raw * sigmoid(for_ignore @ W_ig + b_ig), bf16 out ----------
__global__ __launch_bounds__(256)
void gatev_k(const ushortT* __restrict__ fi, const float* __restrict__ raw,
             const float* __restrict__ wig, const float* __restrict__ big,
             ushortT* __restrict__ vout) {
  __shared__ float sred[4];
  int row = blockIdx.x, tid = threadIdx.x, wave = tid >> 6, lane = tid & 63;
  long off = (long)row * 512;
  float d = b2f(fi[off + tid]) * wig[tid] + b2f(fi[off + tid + 256]) * wig[tid + 256];
  for (int o = 32; o; o >>= 1) d += __shfl_xor(d, o);
  if (lane == 0) sred[wave] = d;
  __syncthreads();
  float g = 1.0f / (1.0f + __expf(-(sred[0] + sred[1] + sred[2] + sred[3] + big[0])));
  vout[off + tid]       = f2b(raw[off + tid] * g);
  vout[off + tid + 256] = f2b(raw[off + tid + 256] * g);
}

// ---------- final gating + output write (f32 out) ----------
__global__ __launch_bounds__(256)
void final_k(const ushortT* __restrict__ fu, const ushortT* __restrict__ A2,
             const float* __restrict__ pd, const float* __restrict__ wu1,
             const float* __restrict__ wu2, const float* __restrict__ bu1,
             const float* __restrict__ bu2, const float* __restrict__ b1p,
             float* __restrict__ outx, float* __restrict__ outg) {
  __shared__ float2 sred[4];
  int row = blockIdx.x, tid = threadIdx.x, wave = tid >> 6, lane = tid & 63;
  long off = (long)row * 512;
  float a2a = b2f(A2[off + tid]), a2b = b2f(A2[off + tid + 256]);
  float d1 = b2f(fu[off + tid]) * wu1[tid] + b2f(fu[off + tid + 256]) * wu1[tid + 256];
  float d2 = a2a * wu2[tid] + a2b * wu2[tid + 256];
  for (int o = 32; o; o >>= 1) { d1 += __shfl_xor(d1, o); d2 += __shfl_xor(d2, o); }
  if (lane == 0) sred[wave] = make_float2(d1, d2);
  __syncthreads();
  float t1 = sred[0].x + sred[1].x + sred[2].x + sred[3].x;
  float t2 = sred[0].y + sred[1].y + sred[2].y + sred[3].y;
  float g = 1.0f / (1.0f + __expf(-(t1 + t2 + bu1[0] + bu2[0] + b1p[0] - 4.0f)));
  outx[off + tid]       = pd[off + tid] * (1.0f - g) + a2a * g;
  outx[off + tid + 256] = pd[off + tid + 256] * (1.0f - g) + a2b * g;
  if (tid == 0) outg[row] = g;
}

// ================= host orchestration =================
extern "C" void kernel_launch(void* const* d_in, const int* in_sizes, int n_in,
                              void* d_out, int out_size, void* d_ws, size_t ws_size,
                              hipStream_t stream)
{
  const float* raw_emb = (const float*)d_in[0];
  const float* rpw     = (const float*)d_in[1];
  const float* post_dec= (const float*)d_in[2];
  const float* rpr     = (const float*)d_in[3];
  const float* questions=(const float*)d_in[4];
  const float* W_k  = (const float*)d_in[5];
  const float* W_ig = (const float*)d_in[6];
  const float* b_ig = (const float*)d_in[7];
  const float* W_u1 = (const float*)d_in[8];
  const float* b_u1 = (const float*)d_in[9];
  const float* W_u2 = (const float*)d_in[10];
  const float* b_u2 = (const float*)d_in[11];
  const float* b1   = (const float*)d_in[12];
  const float* W_ok = (const float*)d_in[13];
  const float* b_ok = (const float*)d_in[14];
  const float* ew_qkv = (const float*)d_in[15];
  const float* ew_bqkv= (const float*)d_in[16];
  const float* ew_wo  = (const float*)d_in[17];
  const float* ew_bo  = (const float*)d_in[18];
  const float* ew_ln  = (const float*)d_in[19];
  const float* ew_wff = (const float*)d_in[20];
  const float* ew_bff = (const float*)d_in[21];
  const float* er_qkv = (const float*)d_in[22];
  const float* er_bqkv= (const float*)d_in[23];
  const float* er_wo  = (const float*)d_in[24];
  const float* er_bo  = (const float*)d_in[25];
  const float* er_ln  = (const float*)d_in[26];
  const float* er_wff = (const float*)d_in[27];
  const float* er_bff = (const float*)d_in[28];
  const int* lookup   = (const int*)d_in[29];

  const size_t MAT = 512ull * 512ull;
  const long SD = 1024 * 512;
  char* wsb = (char*)d_ws;
  size_t off = 0;
  auto alloc = [&](size_t b) { char* p = wsb + off; off = (off + b + 255) & ~(size_t)255; return p; };

  ushortT* WT  = (ushortT*)alloc(26 * MAT * 2);             // transposed bf16 weights
  ushortT* XB  = (ushortT*)alloc(16384ull * 512 * 2);       // encoder state
  ushortT* B1  = (ushortT*)alloc(16384ull * 1024 * 2);      // [q|k] pre-rope / o2 / f2 / vg
  ushortT* SC  = (ushortT*)alloc(16ull * 1024 * 1024 * 2);  // scores/probs
  ushortT* QB  = (ushortT*)alloc(16384ull * 512 * 2);       // q / attn-out / A2
  ushortT* KB  = (ushortT*)alloc(16384ull * 512 * 2);       // k / f1
  ushortT* VT  = (ushortT*)alloc(16384ull * 512 * 2);       // V^T / vg^T
  ushortT* K2  = (ushortT*)alloc(16384ull * 512 * 2);       // k2
  ushortT* KD  = (ushortT*)alloc(8192ull * 512 * 2);        // k_docs
  ushortT* QSB = (ushortT*)alloc(128ull * 512 * 2);         // questions bf16 (padded)
  ushortT* SC2 = (ushortT*)alloc(16384ull * 128 * 2);       // A1 scores / a2 logits
  ushortT* A1S = (ushortT*)alloc(8ull * 128 * 512 * 2);     // A1s (padded rows)
  ushortT* SAT = (ushortT*)alloc(16ull * 512 * 64 * 2);     // selA^T
  float*   PBW = (float*)alloc(8192 * 4);                   // log(rpw)
  float*   PBR = (float*)alloc(16384 * 4);                  // logit(rpr)
  float2*  TAB = (float2*)alloc(1024 * 256 * 8);            // rope sin/cos

  auto gemm = [&](const ushortT* A, const ushortT* Bt, ushortT* C, const float* bias,
                  int bmode, bool gelu, int M, int N, int K,
                  int lda, int ldb, int ldc, int Z, long sA, long sB, long sC) {
    dim3 g(N / 128, M / 128, Z);
    if (gelu) gemm_f<true ><<<g, dim3(256), 0, stream>>>(A, Bt, C, bias, bmode, K, lda, ldb, ldc, sA, sB, sC);
    else      gemm_f<false><<<g, dim3(256), 0, stream>>>(A, Bt, C, bias, bmode, K, lda, ldb, ldc, sA, sB, sC);
  };
  auto tw = [&](const float* src, ushortT* dst, int nm) {
    btrans<float><<<dim3(16, 16, nm), dim3(32, 8), 0, stream>>>(src, dst, 512, 512, (long)MAT, nullptr);
  };
  auto conv = [&](const float* src, ushortT* dst, long n) {
    long n4 = n / 4;
    conv_f2b<<<(unsigned)((n4 + 255) / 256), 256, 0, stream>>>((const float4*)src, (uint2*)dst, n4);
  };

  const float isc512 = 0.044194173824159216f; // 1/sqrt(512)

  // 0. precompute
  bias_prep<<<32, 256, 0, stream>>>(rpw, PBW, 1, 8192);
  bias_prep<<<64, 256, 0, stream>>>(rpr, PBR, 2, 16384);
  rope_tab<<<1024, 256, 0, stream>>>(TAB);
  tw(W_k,    WT + 0 * MAT, 1);
  tw(W_ok,   WT + 1 * MAT, 1);
  tw(ew_qkv, WT + 2 * MAT, 6);
  tw(ew_wo,  WT + 8 * MAT, 2);
  tw(ew_wff, WT + 10 * MAT, 4);
  tw(er_qkv, WT + 14 * MAT, 6);
  tw(er_wo,  WT + 20 * MAT, 2);
  tw(er_wff, WT + 22 * MAT, 4);
  conv(questions, QSB, 64 * 512);   // rows 64..127 stay poison (finite) - never used

  // encoder driver: XB holds bf16(x_in) on entry; leaves XB = encoder output
  auto run_enc = [&](int NB, const ushortT* wqkvT, const float* bqkv,
                     const ushortT* woT, const float* bo, const float* lnp,
                     const ushortT* wffT, const float* bff, const float* pbias) {
    int Mt = NB * 1024;
    for (int l = 0; l < 2; ++l) {
      const ushortT* Wqk = wqkvT + (size_t)(l * 3 + 0) * MAT;  // [Wq^T ; Wk^T] = (1024,512)
      const ushortT* Wv  = wqkvT + (size_t)(l * 3 + 2) * MAT;
      // fused q|k projection: C = (Mt,1024), bias = [bq ; bk] contiguous
      gemm(XB, Wqk, B1, bqkv + (l * 3 + 0) * 512, 1, false, Mt, 1024, 512, 512, 512, 1024, 1, 0, 0, 0);
      rope2_k<<<Mt, 256, 0, stream>>>((const unsigned*)B1, (unsigned*)QB, (unsigned*)KB, TAB);
      // V^T: C(z,512,1024) = Wv^T @ X^T, bias per row (= output dim)
      gemm(Wv, XB, VT, bqkv + (l * 3 + 2) * 512, 2, false, 512, 1024, 512, 512, 512, 1024, NB, 0, SD, SD);
      gemm(QB, KB, SC, nullptr, 0, false, 1024, 1024, 512, 512, 512, 1024, NB, SD, SD, 1024 * 1024);
      softmax1024<<<Mt, 256, 0, stream>>>(SC, pbias, 1024, isc512);
      gemm(SC, VT, QB, nullptr, 0, false, 1024, 512, 1024, 1024, 1024, 512, NB, 1024 * 1024, SD, SD);
      gemm(QB, woT + (size_t)l * MAT, B1, bo + l * 512, 1, false, Mt, 512, 512, 512, 512, 512, 1, 0, 0, 0);
      ln_k<<<Mt, 256, 0, stream>>>(XB, B1, lnp + (l * 4 + 0) * 512, lnp + (l * 4 + 1) * 512);
      gemm(XB, wffT + (size_t)(l * 2 + 0) * MAT, KB, bff + (l * 2 + 0) * 512, 1, true,
           Mt, 512, 512, 512, 512, 512, 1, 0, 0, 0);
      gemm(KB, wffT + (size_t)(l * 2 + 1) * MAT, B1, bff + (l * 2 + 1) * 512, 1, false,
           Mt, 512, 512, 512, 512, 512, 1, 0, 0, 0);
      ln_k<<<Mt, 256, 0, stream>>>(XB, B1, lnp + (l * 4 + 2) * 512, lnp + (l * 4 + 3) * 512);
    }
  };

  // 1. k_docs = raw_emb @ W_k ; encw -> XB = for_ignore
  conv(raw_emb, XB, 8192ull * 512);
  gemm(XB, WT + 0 * MAT, KD, nullptr, 0, false, 8192, 512, 512, 512, 512, 512, 1, 0, 0, 0);
  run_enc(8, WT + 2 * MAT, ew_bqkv, WT + 8 * MAT, ew_bo, ew_ln, WT + 10 * MAT, ew_bff, PBW);

  // 2. v_gate, A1s (M padded to 128; rows 64..127 garbage, never read downstream)
  gatev_k<<<8192, 256, 0, stream>>>(XB, raw_emb, W_ig, b_ig, B1);
  btrans<ushortT><<<dim3(16, 32, 8), dim3(32, 8), 0, stream>>>(B1, VT, 1024, 512, SD, nullptr);
  gemm(QSB, KD, SC2, nullptr, 0, false, 128, 1024, 512, 512, 512, 1024, 8, 0, SD, 128 * 1024);
  softmax1024<<<1024, 256, 0, stream>>>(SC2, PBW, 128, isc512);
  gemm(SC2, VT, A1S, nullptr, 0, false, 128, 512, 1024, 1024, 1024, 512, 8, 128 * 1024, SD, 128 * 512);

  // 3. k2 (before encr mutates XB), then encr -> XB = for_update
  conv(post_dec, XB, 16384ull * 512);
  gemm(XB, WT + 1 * MAT, K2, b_ok, 1, false, 16384, 512, 512, 512, 512, 512, 1, 0, 0, 0);
  run_enc(16, WT + 14 * MAT, er_bqkv, WT + 20 * MAT, er_bo, er_ln, WT + 22 * MAT, er_bff, PBR);

  // 4. a2 (N padded to 128), A2
  gemm(K2, QSB, SC2, nullptr, 0, false, 16384, 128, 512, 512, 512, 128, 1, 0, 0, 0);
  softmax64<<<4096, 256, 0, stream>>>(SC2, 0.125f, 128);
  btrans<ushortT><<<dim3(16, 2, 16), dim3(32, 8), 0, stream>>>(A1S, SAT, 64, 512, 128 * 512, lookup);
  gemm(SC2, SAT, QB, nullptr, 0, false, 1024, 512, 64, 128, 64, 512, 16, 1024 * 128, 512 * 64, SD);

  // 5. final gate + output (f32 out: [out(8388608) | gate(16384)])
  float* outp = (float*)d_out;
  final_k<<<16384, 256, 0, stream>>>(XB, QB, post_dec, W_u1, W_u2, b_u1, b_u2, b1,
                                     outp, outp + 8388608);
}

// Round 7
// 1012.270 us; speedup vs baseline: 1.8346x; 1.0583x over previous
//
#include <hip/hip_runtime.h>
#include <hip/hip_bf16.h>
#include <math.h>

typedef __attribute__((ext_vector_type(8))) short short8;
typedef __attribute__((ext_vector_type(4))) float f32x4;
typedef unsigned short ushortT;

// ---------- helpers ----------
__device__ __forceinline__ unsigned short f2b(float f) {
  union { float f; unsigned u; } v; v.f = f;
  return (unsigned short)((v.u + 0x7FFFu + ((v.u >> 16) & 1u)) >> 16);
}
__device__ __forceinline__ float b2f(unsigned short h) {
  union { unsigned u; float f; } v; v.u = ((unsigned)h) << 16;
  return v.f;
}
__device__ __forceinline__ float gelu_f(float x) {
  return 0.5f * x * (1.0f + tanhf(0.7978845608028654f * (x + 0.044715f * x * x * x)));
}

// async 16B global -> LDS DMA. LDS dest = wave-uniform base + lane*16.
__device__ __forceinline__ void async16(ushortT* lds, const ushortT* g) {
  __builtin_amdgcn_global_load_lds(
      (const __attribute__((address_space(1))) void*)g,
      (__attribute__((address_space(3))) void*)lds, 16, 0, 0);
}

// ---------- GEMM: C(M,N) = A(M,K) @ Bt(N,K)^T, bf16 in/out, f32 acc ----------
// 128x128 tile, BK=32, double-buffered async LDS staging, XOR-swizzled columns,
// LDS-staged coalesced C writes. EMODE: 0=plain, 1=gelu, 2=rope split (C=q,C2=k).
// bias: bmode 0=none, 1=col, 2=row; effective bias ptr = bias + z*bstride.
// v = acc*scale + bias. REQUIRES: M,N mult of 128; K mult of 32; lds mult of 8.
template<int EMODE>
__global__ __launch_bounds__(256, 4)
void gemm_f(const ushortT* __restrict__ A, const ushortT* __restrict__ Bt,
            ushortT* __restrict__ C, ushortT* __restrict__ C2,
            const float* __restrict__ bias, int bmode, float scale, long bstride,
            int K, int lda, int ldb, int ldc,
            long sA, long sB, long sC, const float2* __restrict__ tab)
{
  __shared__ ushortT lds[2][2][128 * 32];   // reused as 128x128 bf16 C-tile after k-loop
  const int z = blockIdx.z;
  A += (long)z * sA;
  Bt += (long)z * sB;
  const long coff = (long)z * sC;
  const int bm = blockIdx.y * 128, bn = blockIdx.x * 128;
  const int tid = threadIdx.x, wave = tid >> 6, lane = tid & 63;
  const int wm = (wave >> 1) << 6, wn = (wave & 1) << 6;
  const int l15 = lane & 15, quad = lane >> 4;

  const ushortT* gA[2]; const ushortT* gB[2];
  int lchunk[2];
#pragma unroll
  for (int q = 0; q < 2; ++q) {
    int r = 32 * wave + 16 * q + (lane >> 2);
    int sw = (((lane & 3) ^ ((r >> 1) & 3)) << 3);
    gA[q] = A + (long)(bm + r) * lda + sw;
    gB[q] = Bt + (long)(bn + r) * ldb + sw;
    lchunk[q] = (wave * 2 + q) * 512;
  }

  f32x4 acc[4][4];
#pragma unroll
  for (int i = 0; i < 4; ++i)
#pragma unroll
    for (int j = 0; j < 4; ++j) acc[i][j] = (f32x4){0.f, 0.f, 0.f, 0.f};

  const int x0 = (l15 >> 1) & 3;
  const int nk = K >> 5;

#pragma unroll
  for (int q = 0; q < 2; ++q) {
    async16(&lds[0][0][lchunk[q]], gA[q]);
    async16(&lds[0][1][lchunk[q]], gB[q]);
  }

  int cur = 0;
  for (int k = 0; k < nk; ++k) {
    __syncthreads();
    if (k + 1 < nk) {
      int k0 = (k + 1) << 5;
#pragma unroll
      for (int q = 0; q < 2; ++q) {
        async16(&lds[cur ^ 1][0][lchunk[q]], gA[q] + k0);
        async16(&lds[cur ^ 1][1][lchunk[q]], gB[q] + k0);
      }
    }
    short8 aF[4], bF[4];
#pragma unroll
    for (int t = 0; t < 4; ++t) {
      int ra = (wm + t * 16 + l15) << 5;
      aF[t] = *(const short8*)&lds[cur][0][ra + ((quad ^ x0) << 3)];
      int rb = (wn + t * 16 + l15) << 5;
      bF[t] = *(const short8*)&lds[cur][1][rb + ((quad ^ x0) << 3)];
    }
#pragma unroll
    for (int i = 0; i < 4; ++i)
#pragma unroll
      for (int j = 0; j < 4; ++j)
        acc[i][j] = __builtin_amdgcn_mfma_f32_16x16x32_bf16(aF[i], bF[j], acc[i][j], 0, 0, 0);
    cur ^= 1;
  }

  // epilogue: acc*scale + bias (+gelu) -> LDS C-tile -> coalesced writes (or rope split)
  __syncthreads();
  ushortT* ct = &lds[0][0][0];
  const float* bz = bias + (long)z * bstride;
#pragma unroll
  for (int j = 0; j < 4; ++j) {
    int tcol = wn + j * 16 + l15;
    float cbv = (bmode == 1) ? bz[bn + tcol] : 0.0f;
#pragma unroll
    for (int i = 0; i < 4; ++i) {
      int row0 = wm + i * 16 + (quad << 2);
#pragma unroll
      for (int r = 0; r < 4; ++r) {
        int row = row0 + r;
        float bv = (bmode == 2) ? bz[bm + row] : cbv;
        float v = acc[i][j][r] * scale + bv;
        if (EMODE == 1) v = gelu_f(v);
        ct[(row << 7) + tcol] = f2b(v);
      }
    }
  }
  __syncthreads();

  if (EMODE == 2) {
    // rope + split into q (cols 0..511) / k (cols 512..1023), dest ld = 512
    const bool isq = (bn < 512);
    ushortT* dbase = isq ? C : C2;
    const int cbase = isq ? bn : bn - 512;
#pragma unroll
    for (int it = 0; it < 8; ++it) {
      int trow = it * 16 + (tid >> 4);
      int tcol = (tid & 15) << 3;
      uint4 u = *(const uint4*)&ct[(trow << 7) + tcol];
      int grow = bm + trow;
      int pos = grow & 1023;
      int pair0 = (cbase + tcol) >> 1;
      const float2* tp = &tab[(pos << 8) + pair0];
      unsigned w[4] = {u.x, u.y, u.z, u.w};
      uint4 o;
      unsigned* op = (unsigned*)&o;
#pragma unroll
      for (int p = 0; p < 4; ++p) {
        float2 sc = tp[p];
        float x1 = b2f((ushortT)(w[p] & 0xFFFFu));
        float x2 = b2f((ushortT)(w[p] >> 16));
        float o1 = x1 * sc.y - x2 * sc.x;
        float o2 = x1 * sc.x + x2 * sc.y;
        op[p] = (unsigned)f2b(o1) | ((unsigned)f2b(o2) << 16);
      }
      *(uint4*)&dbase[(long)grow * 512 + cbase + tcol] = o;
    }
  } else {
#pragma unroll
    for (int it = 0; it < 8; ++it) {
      int trow = it * 16 + (tid >> 4);
      int tcol = (tid & 15) << 3;
      *(uint4*)&C[coff + (long)(bm + trow) * ldc + bn + tcol] =
          *(const uint4*)&ct[(trow << 7) + tcol];
    }
  }
}

// ---------- batched tiled transpose (z,R,C)->(z,C,R) bf16->bf16, optional gather ----------
__global__ void btrans(const ushortT* __restrict__ in, ushortT* __restrict__ out,
                       int R, int C, long ibs, const int* __restrict__ gather) {
  __shared__ float tile[32][33];
  int z = blockIdx.z;
  long ib = (long)(gather ? gather[z] : z) * ibs;
  long ob = (long)z * (long)R * C;
  int c0 = blockIdx.x << 5, r0 = blockIdx.y << 5;
  int tx = threadIdx.x, ty = threadIdx.y;
#pragma unroll
  for (int dy = 0; dy < 32; dy += 8)
    tile[ty + dy][tx] = b2f(in[ib + (long)(r0 + ty + dy) * C + c0 + tx]);
  __syncthreads();
#pragma unroll
  for (int dy = 0; dy < 32; dy += 8)
    out[ob + (long)(c0 + ty + dy) * R + r0 + tx] = f2b(tile[tx][ty + dy]);
}

// ---------- all 26 weight transposes in one dispatch: f32 (512,512) -> bf16 W^T ----------
struct WSrc { const float* p[8]; int c[8]; };
__global__ void wtrans_all(WSrc ws, ushortT* __restrict__ out) {
  __shared__ float tile[32][33];
  int z = blockIdx.z;
  int g = 0, base = 0;
  while (z - base >= ws.c[g]) { base += ws.c[g]; ++g; }
  const float* src = ws.p[g] + (size_t)(z - base) * 262144;
  ushortT* dst = out + (size_t)z * 262144;
  int c0 = blockIdx.x << 5, r0 = blockIdx.y << 5;
  int tx = threadIdx.x, ty = threadIdx.y;
#pragma unroll
  for (int dy = 0; dy < 32; dy += 8)
    tile[ty + dy][tx] = src[(long)(r0 + ty + dy) * 512 + c0 + tx];
  __syncthreads();
#pragma unroll
  for (int dy = 0; dy < 32; dy += 8)
    dst[(long)(c0 + ty + dy) * 512 + r0 + tx] = f2b(tile[tx][ty + dy]);
}

// ---------- fused setup: softmax biases, rope table, f32->bf16 convs ----------
__device__ __forceinline__ void conv4(const float4* in, uint2* out, long i) {
  float4 v = in[i];
  uint2 r;
  r.x = (unsigned)f2b(v.x) | ((unsigned)f2b(v.y) << 16);
  r.y = (unsigned)f2b(v.z) | ((unsigned)f2b(v.w) << 16);
  out[i] = r;
}
__global__ __launch_bounds__(256)
void setup_k(const float* __restrict__ rpw, const float* __restrict__ rpr,
             const float* __restrict__ questions, const float* __restrict__ raw,
             const float* __restrict__ pd,
             float* __restrict__ pbw, float* __restrict__ pbr, float2* __restrict__ tab,
             uint2* __restrict__ qsb, uint2* __restrict__ rab, uint2* __restrict__ pdb) {
  int b = blockIdx.x, t = threadIdx.x;
  if (b < 32) { int i = b * 256 + t; float v = rpw[i]; pbw[i] = __logf(v); return; }
  b -= 32;
  if (b < 64) { int i = b * 256 + t; float v = rpr[i]; pbr[i] = __logf(v) - log1pf(-v); return; }
  b -= 64;
  if (b < 1024) {
    float inv = __expf(-(float)t * 0.035977892078032f);
    float s, c;
    sincosf((float)b * inv, &s, &c);
    tab[(b << 8) + t] = make_float2(s, c);
    return;
  }
  b -= 1024;
  if (b < 32) { conv4((const float4*)questions, qsb, (long)b * 256 + t); return; }
  b -= 32;
  if (b < 4096) { conv4((const float4*)raw, rab, (long)b * 256 + t); return; }
  b -= 4096;
  conv4((const float4*)pd, pdb, (long)b * 256 + t);
}

// ---------- in-place softmax, L=1024 (bias/scale already folded into scores) ----------
__global__ __launch_bounds__(256)
void softmax1024(ushortT* __restrict__ x) {
  __shared__ float sred[8];
  int row = blockIdx.x, tid = threadIdx.x, wave = tid >> 6, lane = tid & 63;
  ushortT* xr = x + (long)row * 1024;
  uint2 u = ((const uint2*)xr)[tid];
  float t0 = b2f((ushortT)(u.x & 0xFFFFu));
  float t1 = b2f((ushortT)(u.x >> 16));
  float t2 = b2f((ushortT)(u.y & 0xFFFFu));
  float t3 = b2f((ushortT)(u.y >> 16));
  float m = fmaxf(fmaxf(t0, t1), fmaxf(t2, t3));
  for (int o = 32; o; o >>= 1) m = fmaxf(m, __shfl_xor(m, o));
  if (lane == 0) sred[wave] = m;
  __syncthreads();
  m = fmaxf(fmaxf(sred[0], sred[1]), fmaxf(sred[2], sred[3]));
  float e0 = __expf(t0 - m), e1 = __expf(t1 - m), e2 = __expf(t2 - m), e3 = __expf(t3 - m);
  float s = e0 + e1 + e2 + e3;
  for (int o = 32; o; o >>= 1) s += __shfl_xor(s, o);
  if (lane == 0) sred[4 + wave] = s;
  __syncthreads();
  float inv = 1.0f / (sred[4] + sred[5] + sred[6] + sred[7]);
  uint2 r;
  r.x = (unsigned)f2b(e0 * inv) | ((unsigned)f2b(e1 * inv) << 16);
  r.y = (unsigned)f2b(e2 * inv) | ((unsigned)f2b(e3 * inv) << 16);
  ((uint2*)xr)[tid] = r;
}

// ---------- in-place softmax, L=64 (one wave per row; scale pre-folded) ----------
__global__ __launch_bounds__(256)
void softmax64(ushortT* __restrict__ x, int ldr) {
  int row = blockIdx.x * 4 + (threadIdx.x >> 6), lane = threadIdx.x & 63;
  ushortT* xr = x + (long)row * ldr;
  float t = b2f(xr[lane]);
  float m = t;
  for (int o = 32; o; o >>= 1) m = fmaxf(m, __shfl_xor(m, o));
  float e = __expf(t - m), s = e;
  for (int o = 32; o; o >>= 1) s += __shfl_xor(s, o);
  xr[lane] = f2b(e / s);
}

// ---------- fused residual + LayerNorm: dst = LN(src + res), D=512 ----------
__global__ __launch_bounds__(256)
void ln_k(const ushortT* __restrict__ src, const ushortT* __restrict__ res,
          const float* __restrict__ gamma, const float* __restrict__ beta,
          ushortT* __restrict__ dst) {
  __shared__ float2 sred[4];
  int row = blockIdx.x, tid = threadIdx.x, wave = tid >> 6, lane = tid & 63;
  long off = (long)row * 512;
  float a = b2f(src[off + tid]) + b2f(res[off + tid]);
  float b = b2f(src[off + tid + 256]) + b2f(res[off + tid + 256]);
  float s = a + b, q = a * a + b * b;
  for (int o = 32; o; o >>= 1) { s += __shfl_xor(s, o); q += __shfl_xor(q, o); }
  if (lane == 0) sred[wave] = make_float2(s, q);
  __syncthreads();
  float ts = sred[0].x + sred[1].x + sred[2].x + sred[3].x;
  float tq = sred[0].y + sred[1].y + sred[2].y + sred[3].y;
  float mean = ts * (1.0f / 512.0f);
  float var = tq * (1.0f / 512.0f) - mean * mean;
  float rstd = rsqrtf(fmaxf(var, 0.f) + 1e-5f);
  dst[off + tid]       = f2b((a - mean) * rstd * gamma[tid]       + beta[tid]);
  dst[off + tid + 256] = f2b((b - mean) * rstd * gamma[tid + 256] + beta[tid + 256]);
}

// ---------- v = raw * sigmoid(for_ignore @ W_ig + b_ig), bf16 out ----------
__global__ __launch_bounds__(256)
void gatev_k(const ushortT* __restrict__ fi, const float* __restrict__ raw,
             const float* __restrict__ wig, const float* __restrict__ big,
             ushortT* __restrict__ vout) {
  __shared__ float sred[4];
  int row = blockIdx.x, tid = threadIdx.x, wave = tid >> 6, lane = tid & 63;
  long off = (long)row * 512;
  float d = b2f(fi[off + tid]) * wig[tid] + b2f(fi[off + tid + 256]) * wig[tid + 256];
  for (int o = 32; o; o >>= 1) d += __shfl_xor(d, o);
  if (lane == 0) sred[wave] = d;
  __syncthreads();
  float g = 1.0f / (1.0f + __expf(-(sred[0] + sred[1] + sred[2] + sred[3] + big[0])));
  vout[off + tid]       = f2b(raw[off + tid] * g);
  vout[off + tid + 256] = f2b(raw[off + tid + 256] * g);
}

// ---------- final gating + output write (f32 out) ----------
__global__ __launch_bounds__(256)
void final_k(const ushortT* __restrict__ fu, const ushortT* __restrict__ A2,
             const float* __restrict__ pd, const float* __restrict__ wu1,
             const float* __restrict__ wu2, const float* __restrict__ bu1,
             const float* __restrict__ bu2, const float* __restrict__ b1p,
             float* __restrict__ outx, float* __restrict__ outg) {
  __shared__ float2 sred[4];
  int row = blockIdx.x, tid = threadIdx.x, wave = tid >> 6, lane = tid & 63;
  long off = (long)row * 512;
  float a2a = b2f(A2[off + tid]), a2b = b2f(A2[off + tid + 256]);
  float d1 = b2f(fu[off + tid]) * wu1[tid] + b2f(fu[off + tid + 256]) * wu1[tid + 256];
  float d2 = a2a * wu2[tid] + a2b * wu2[tid + 256];
  for (int o = 32; o; o >>= 1) { d1 += __shfl_xor(d1, o); d2 += __shfl_xor(d2, o); }
  if (lane == 0) sred[wave] = make_float2(d1, d2);
  __syncthreads();
  float t1 = sred[0].x + sred[1].x + sred[2].x + sred[3].x;
  float t2 = sred[0].y + sred[1].y + sred[2].y + sred[3].y;
  float g = 1.0f / (1.0f + __expf(-(t1 + t2 + bu1[0] + bu2[0] + b1p[0] - 4.0f)));
  outx[off + tid]       = pd[off + tid] * (1.0f - g) + a2a * g;
  outx[off + tid + 256] = pd[off + tid + 256] * (1.0f - g) + a2b * g;
  if (tid == 0) outg[row] = g;
}

// ================= host orchestration =================
extern "C" void kernel_launch(void* const* d_in, const int* in_sizes, int n_in,
                              void* d_out, int out_size, void* d_ws, size_t ws_size,
                              hipStream_t stream)
{
  const float* raw_emb = (const float*)d_in[0];
  const float* rpw     = (const float*)d_in[1];
  const float* post_dec= (const float*)d_in[2];
  const float* rpr     = (const float*)d_in[3];
  const float* questions=(const float*)d_in[4];
  const float* W_k  = (const float*)d_in[5];
  const float* W_ig = (const float*)d_in[6];
  const float* b_ig = (const float*)d_in[7];
  const float* W_u1 = (const float*)d_in[8];
  const float* b_u1 = (const float*)d_in[9];
  const float* W_u2 = (const float*)d_in[10];
  const float* b_u2 = (const float*)d_in[11];
  const float* b1   = (const float*)d_in[12];
  const float* W_ok = (const float*)d_in[13];
  const float* b_ok = (const float*)d_in[14];
  const float* ew_qkv = (const float*)d_in[15];
  const float* ew_bqkv= (const float*)d_in[16];
  const float* ew_wo  = (const float*)d_in[17];
  const float* ew_bo  = (const float*)d_in[18];
  const float* ew_ln  = (const float*)d_in[19];
  const float* ew_wff = (const float*)d_in[20];
  const float* ew_bff = (const float*)d_in[21];
  const float* er_qkv = (const float*)d_in[22];
  const float* er_bqkv= (const float*)d_in[23];
  const float* er_wo  = (const float*)d_in[24];
  const float* er_bo  = (const float*)d_in[25];
  const float* er_ln  = (const float*)d_in[26];
  const float* er_wff = (const float*)d_in[27];
  const float* er_bff = (const float*)d_in[28];
  const int* lookup   = (const int*)d_in[29];

  const size_t MAT = 512ull * 512ull;
  const long SD = 1024 * 512;
  char* wsb = (char*)d_ws;
  size_t off = 0;
  auto alloc = [&](size_t b) { char* p = wsb + off; off = (off + b + 255) & ~(size_t)255; return p; };

  ushortT* WT  = (ushortT*)alloc(26 * MAT * 2);             // transposed bf16 weights
  ushortT* RAB = (ushortT*)alloc(8192ull * 512 * 2);        // bf16 raw_emb
  ushortT* PDB = (ushortT*)alloc(16384ull * 512 * 2);       // bf16 post_dec
  ushortT* XB  = (ushortT*)alloc(16384ull * 512 * 2);       // encoder state
  ushortT* B1  = (ushortT*)alloc(16384ull * 512 * 2);       // Wo-out / FF2-out / vg
  ushortT* SC  = (ushortT*)alloc(16ull * 1024 * 1024 * 2);  // scores/probs
  ushortT* QB  = (ushortT*)alloc(16384ull * 512 * 2);       // q / attn-out / A2
  ushortT* KB  = (ushortT*)alloc(16384ull * 512 * 2);       // k / f1
  ushortT* VT  = (ushortT*)alloc(16384ull * 512 * 2);       // V^T / vg^T
  ushortT* K2  = (ushortT*)alloc(16384ull * 512 * 2);       // k2
  ushortT* KD  = (ushortT*)alloc(8192ull * 512 * 2);        // k_docs
  ushortT* QSB = (ushortT*)alloc(128ull * 512 * 2);         // questions bf16 (padded)
  ushortT* SC2 = (ushortT*)alloc(16384ull * 128 * 2);       // A1 scores / a2 logits
  ushortT* A1S = (ushortT*)alloc(8ull * 128 * 512 * 2);     // A1s (padded rows)
  ushortT* SAT = (ushortT*)alloc(16ull * 512 * 64 * 2);     // selA^T
  float*   PBW = (float*)alloc(8192 * 4);                   // log(rpw)
  float*   PBR = (float*)alloc(16384 * 4);                  // logit(rpr)
  float2*  TAB = (float2*)alloc(1024 * 256 * 8);            // rope sin/cos

  // EMODE: 0 plain, 1 gelu, 2 rope-split
  auto gemm = [&](int emode, const ushortT* A, const ushortT* Bt, ushortT* C, ushortT* C2,
                  const float* bias, int bmode, float scale, long bstride,
                  int M, int N, int K, int lda, int ldb, int ldc,
                  int Z, long sA, long sB, long sC) {
    dim3 g(N / 128, M / 128, Z);
    if (emode == 0)
      gemm_f<0><<<g, dim3(256), 0, stream>>>(A, Bt, C, C2, bias, bmode, scale, bstride,
                                             K, lda, ldb, ldc, sA, sB, sC, TAB);
    else if (emode == 1)
      gemm_f<1><<<g, dim3(256), 0, stream>>>(A, Bt, C, C2, bias, bmode, scale, bstride,
                                             K, lda, ldb, ldc, sA, sB, sC, TAB);
    else
      gemm_f<2><<<g, dim3(256), 0, stream>>>(A, Bt, C, C2, bias, bmode, scale, bstride,
                                             K, lda, ldb, ldc, sA, sB, sC, TAB);
  };

  const float isc512 = 0.044194173824159216f; // 1/sqrt(512)

  // 0. setup: all weight transposes (1 dispatch) + biases/rope-table/convs (1 dispatch)
  WSrc wsrc;
  wsrc.p[0] = W_k;    wsrc.c[0] = 1;
  wsrc.p[1] = W_ok;   wsrc.c[1] = 1;
  wsrc.p[2] = ew_qkv; wsrc.c[2] = 6;
  wsrc.p[3] = ew_wo;  wsrc.c[3] = 2;
  wsrc.p[4] = ew_wff; wsrc.c[4] = 4;
  wsrc.p[5] = er_qkv; wsrc.c[5] = 6;
  wsrc.p[6] = er_wo;  wsrc.c[6] = 2;
  wsrc.p[7] = er_wff; wsrc.c[7] = 4;
  wtrans_all<<<dim3(16, 16, 26), dim3(32, 8), 0, stream>>>(wsrc, WT);
  setup_k<<<13440, 256, 0, stream>>>(rpw, rpr, questions, raw_emb, post_dec,
                                     PBW, PBR, TAB, (uint2*)QSB, (uint2*)RAB, (uint2*)PDB);

  // encoder driver: x0 = layer-0 input state (bf16); leaves XB = encoder output
  auto run_enc = [&](int NB, const ushortT* x0, const ushortT* wqkvT, const float* bqkv,
                     const ushortT* woT, const float* bo, const float* lnp,
                     const ushortT* wffT, const float* bff, const float* pbias) {
    int Mt = NB * 1024;
    for (int l = 0; l < 2; ++l) {
      const ushortT* xs = (l == 0) ? x0 : XB;
      const ushortT* Wqk = wqkvT + (size_t)(l * 3 + 0) * MAT;  // [Wq^T ; Wk^T]
      const ushortT* Wv  = wqkvT + (size_t)(l * 3 + 2) * MAT;
      // fused q|k projection + bias + rope, writes QB,KB directly
      gemm(2, xs, Wqk, QB, KB, bqkv + (l * 3 + 0) * 512, 1, 1.0f, 0,
           Mt, 1024, 512, 512, 512, 0, 1, 0, 0, 0);
      // V^T: C(z,512,1024) = Wv^T @ X^T, bias per row (= output dim)
      gemm(0, Wv, xs, VT, nullptr, bqkv + (l * 3 + 2) * 512, 2, 1.0f, 0,
           512, 1024, 512, 512, 512, 1024, NB, 0, SD, SD);
      // scores with fused scale + per-batch positional bias
      gemm(0, QB, KB, SC, nullptr, pbias, 1, isc512, 1024,
           1024, 1024, 512, 512, 512, 1024, NB, SD, SD, 1024 * 1024);
      softmax1024<<<Mt, 256, 0, stream>>>(SC);
      gemm(0, SC, VT, QB, nullptr, nullptr, 0, 1.0f, 0,
           1024, 512, 1024, 1024, 1024, 512, NB, 1024 * 1024, SD, SD);
      gemm(0, QB, woT + (size_t)l * MAT, B1, nullptr, bo + l * 512, 1, 1.0f, 0,
           Mt, 512, 512, 512, 512, 512, 1, 0, 0, 0);
      ln_k<<<Mt, 256, 0, stream>>>(xs, B1, lnp + (l * 4 + 0) * 512, lnp + (l * 4 + 1) * 512, XB);
      gemm(1, XB, wffT + (size_t)(l * 2 + 0) * MAT, KB, nullptr, bff + (l * 2 + 0) * 512, 1, 1.0f, 0,
           Mt, 512, 512, 512, 512, 512, 1, 0, 0, 0);
      gemm(0, KB, wffT + (size_t)(l * 2 + 1) * MAT, B1, nullptr, bff + (l * 2 + 1) * 512, 1, 1.0f, 0,
           Mt, 512, 512, 512, 512, 512, 1, 0, 0, 0);
      ln_k<<<Mt, 256, 0, stream>>>(XB, B1, lnp + (l * 4 + 2) * 512, lnp + (l * 4 + 3) * 512, XB);
    }
  };

  // 1. k_docs = raw_emb @ W_k ; encw -> XB = for_ignore
  gemm(0, RAB, WT + 0 * MAT, KD, nullptr, nullptr, 0, 1.0f, 0,
       8192, 512, 512, 512, 512, 512, 1, 0, 0, 0);
  run_enc(8, RAB, WT + 2 * MAT, ew_bqkv, WT + 8 * MAT, ew_bo, ew_ln, WT + 10 * MAT, ew_bff, PBW);

  // 2. v_gate, A1s (M padded to 128; rows 64..127 garbage, never read downstream)
  gatev_k<<<8192, 256, 0, stream>>>(XB, raw_emb, W_ig, b_ig, B1);
  btrans<<<dim3(16, 32, 8), dim3(32, 8), 0, stream>>>(B1, VT, 1024, 512, SD, nullptr);
  gemm(0, QSB, KD, SC2, nullptr, PBW, 1, isc512, 1024,
       128, 1024, 512, 512, 512, 1024, 8, 0, SD, 128 * 1024);
  softmax1024<<<1024, 256, 0, stream>>>(SC2);
  gemm(0, SC2, VT, A1S, nullptr, nullptr, 0, 1.0f, 0,
       128, 512, 1024, 1024, 1024, 512, 8, 128 * 1024, SD, 128 * 512);

  // 3. k2 (from PDB), then encr -> XB = for_update
  gemm(0, PDB, WT + 1 * MAT, K2, nullptr, b_ok, 1, 1.0f, 0,
       16384, 512, 512, 512, 512, 512, 1, 0, 0, 0);
  run_enc(16, PDB, WT + 14 * MAT, er_bqkv, WT + 20 * MAT, er_bo, er_ln, WT + 22 * MAT, er_bff, PBR);

  // 4. a2 (N padded to 128, scale fused), A2
  gemm(0, K2, QSB, SC2, nullptr, nullptr, 0, 0.125f, 0,
       16384, 128, 512, 512, 512, 128, 1, 0, 0, 0);
  softmax64<<<4096, 256, 0, stream>>>(SC2, 128);
  btrans<<<dim3(16, 2, 16), dim3(32, 8), 0, stream>>>(A1S, SAT, 64, 512, 128 * 512, lookup);
  gemm(0, SC2, SAT, QB, nullptr, nullptr, 0, 1.0f, 0,
       1024, 512, 64, 128, 64, 512, 16, 1024 * 128, 512 * 64, SD);

  // 5. final gate + output (f32 out: [out(8388608) | gate(16384)])
  float* outp = (float*)d_out;
  final_k<<<16384, 256, 0, stream>>>(XB, QB, post_dec, W_u1, W_u2, b_u1, b_u2, b1,
                                     outp, outp + 8388608);
}